// Round 1
// baseline (233.366 us; speedup 1.0000x reference)
//
#include <hip/hip_runtime.h>

// Problem: B=4, T=2048, C=1024, H=64. fp32 in/out, bf16 MFMA internally.
// ws layout (in u16 elements):
//   [0,        524288)  q  bf16  [b*2048+t][64]
//   [524288,  1048576)  k  bf16  [b*2048+t][64]
//   [1048576, 1572864)  vT bf16  [b][h][t]   (b*131072 + h*2048 + t)
//   [1572864, 1769472)  wT bf16  [sel][h][c] (sel*65536 + h*1024 + c)
// total ws bytes = 3,538,944

typedef __attribute__((ext_vector_type(8))) short short8;
typedef __attribute__((ext_vector_type(4))) float f32x4;
typedef __attribute__((ext_vector_type(8))) unsigned short ushort8;

#define NTOT 524288   // 8192*64

__device__ __forceinline__ unsigned short f2bf(float f) {
    // round-to-nearest-even fp32 -> bf16
    unsigned int u = __builtin_bit_cast(unsigned int, f);
    return (unsigned short)((u + 0x7fffu + ((u >> 16) & 1u)) >> 16);
}

__device__ __forceinline__ short8 pack8(float4 a, float4 b) {
    short8 r;
    r[0] = (short)f2bf(a.x); r[1] = (short)f2bf(a.y);
    r[2] = (short)f2bf(a.z); r[3] = (short)f2bf(a.w);
    r[4] = (short)f2bf(b.x); r[5] = (short)f2bf(b.y);
    r[6] = (short)f2bf(b.z); r[7] = (short)f2bf(b.w);
    return r;
}

// ---------------------------------------------------------------------------
// Kernel 1: transpose W (fp32 [1024][64]) -> wT bf16 [64][1024], x3 matrices
// ---------------------------------------------------------------------------
__global__ __launch_bounds__(256) void wtrans_kernel(
    const float* __restrict__ Wq, const float* __restrict__ Wk,
    const float* __restrict__ Wv, unsigned short* __restrict__ wt)
{
    const int sel = blockIdx.x;
    const int c0  = blockIdx.y * 64;
    const float* W = (sel == 0) ? Wq : ((sel == 1) ? Wk : Wv);
    __shared__ unsigned short tile[64][72];  // [c][h], pad to dodge conflicts
    const int tid = threadIdx.x;
    {
        const int c  = tid >> 2;          // 0..63
        const int hg = (tid & 3) * 16;    // 0,16,32,48
        const float* src = W + (size_t)(c0 + c) * 64 + hg;
        #pragma unroll
        for (int i = 0; i < 16; i++) tile[c][hg + i] = f2bf(src[i]);
    }
    __syncthreads();
    {
        const int h  = tid >> 2;
        const int cg = (tid & 3) * 16;
        unsigned short* dst = wt + ((size_t)sel * 64 + h) * 1024 + c0 + cg;
        #pragma unroll
        for (int i = 0; i < 16; i++) dst[i] = tile[cg + i][h];  // wT[h][c]=W[c][h]
    }
}

// ---------------------------------------------------------------------------
// Kernel 2: projections. sel=0,1 -> q,k ([t][h]); sel=2 -> vT ([h][t]).
// MFMA 16x16x32 bf16. A-frag: A[m=lane&15][k=quad*8+j]. B-frag:
// B[k=quad*8+j][n=lane&15]. D: row=quad*4+reg, col=lane&15.
// ---------------------------------------------------------------------------
__global__ __launch_bounds__(256) void proj_kernel(
    const float* __restrict__ x, const unsigned short* __restrict__ wt,
    unsigned short* __restrict__ ws)
{
    const int sel  = blockIdx.y;
    const int m0   = blockIdx.x * 64;
    const int tid  = threadIdx.x;
    const int wave = tid >> 6, lane = tid & 63;
    const int quad = lane >> 4, l16 = lane & 15;

    __shared__ unsigned short vt_lds[64][72];  // [h][t] for sel==2 epilogue

    const unsigned short* wsel = wt + (size_t)sel * 65536;
    f32x4 acc[4] = {};

    if (sel < 2) {
        // D[m=t][n=h]: A = x rows, B = W (k-contig via wT)
        const float* xrow = x + (size_t)(m0 + wave * 16 + l16) * 1024 + quad * 8;
        for (int kk = 0; kk < 1024; kk += 32) {
            float4 xa = *(const float4*)(xrow + kk);
            float4 xb = *(const float4*)(xrow + kk + 4);
            short8 af = pack8(xa, xb);
            #pragma unroll
            for (int nt = 0; nt < 4; nt++) {
                short8 bf = *(const short8*)(wsel + (size_t)(nt * 16 + l16) * 1024 + kk + quad * 8);
                acc[nt] = __builtin_amdgcn_mfma_f32_16x16x32_bf16(af, bf, acc[nt], 0, 0, 0);
            }
        }
        unsigned short* dst = ws + (size_t)sel * NTOT;
        const int mo = m0 + wave * 16 + quad * 4;
        #pragma unroll
        for (int nt = 0; nt < 4; nt++)
            #pragma unroll
            for (int r = 0; r < 4; r++)
                dst[(size_t)(mo + r) * 64 + nt * 16 + l16] = f2bf(acc[nt][r]);
    } else {
        // vT: D[m=h][n=t]: A = wT rows (h), B = x^T (same frag pattern as x rows)
        const unsigned short* arow = wsel + (size_t)(wave * 16 + l16) * 1024 + quad * 8;
        const float* xbase = x + (size_t)(m0 + l16) * 1024 + quad * 8;
        for (int kk = 0; kk < 1024; kk += 32) {
            short8 af = *(const short8*)(arow + kk);
            #pragma unroll
            for (int nt = 0; nt < 4; nt++) {
                const float* src = xbase + (size_t)nt * 16 * 1024 + kk;
                float4 xa = *(const float4*)(src);
                float4 xb = *(const float4*)(src + 4);
                short8 bf = pack8(xa, xb);
                acc[nt] = __builtin_amdgcn_mfma_f32_16x16x32_bf16(af, bf, acc[nt], 0, 0, 0);
            }
        }
        // acc[nt][r] = vT[h = wave*16+quad*4+r][t = m0 + nt*16 + l16]
        #pragma unroll
        for (int nt = 0; nt < 4; nt++)
            #pragma unroll
            for (int r = 0; r < 4; r++)
                vt_lds[wave * 16 + quad * 4 + r][nt * 16 + l16] = f2bf(acc[nt][r]);
        __syncthreads();
        const int b = m0 >> 11, t0 = m0 & 2047;
        const int h = tid >> 2, tseg = (tid & 3) * 16;
        unsigned short* dst = ws + 2 * NTOT + (size_t)b * 131072 + (size_t)h * 2048 + t0 + tseg;
        *(ushort8*)(dst)     = *(const ushort8*)&vt_lds[h][tseg];
        *(ushort8*)(dst + 8) = *(const ushort8*)&vt_lds[h][tseg + 8];
    }
}

// ---------------------------------------------------------------------------
// Kernel 3: fused causal attention, flash-style online softmax.
// Block: 64 q-rows (16/wave), iterate k-tiles of 64. grid = (T/64, B).
// ---------------------------------------------------------------------------
__global__ __launch_bounds__(256) void attn_kernel(
    const unsigned short* __restrict__ ws, float* __restrict__ out)
{
    const int b  = blockIdx.y;
    const int bt = blockIdx.x;
    const int q0 = bt * 64;
    const int tid  = threadIdx.x;
    const int wave = tid >> 6, lane = tid & 63;
    const int quad = lane >> 4, l16 = lane & 15;

    const unsigned short* Q  = ws + (size_t)b * 131072;
    const unsigned short* K  = ws + NTOT + (size_t)b * 131072;
    const unsigned short* VT = ws + 2 * NTOT + (size_t)b * 131072;

    __shared__ unsigned short p_lds[4][16][72];  // per-wave P tile, 144B rows

    // Q fragments held in registers for the whole block
    const int qrow = q0 + wave * 16 + l16;
    short8 qf0 = *(const short8*)(Q + (size_t)qrow * 64 + quad * 8);
    short8 qf1 = *(const short8*)(Q + (size_t)qrow * 64 + 32 + quad * 8);

    f32x4 o[4] = {};
    float m_i[4], l_i[4];
    #pragma unroll
    for (int r = 0; r < 4; r++) { m_i[r] = -1e30f; l_i[r] = 0.f; }

    const int qi = q0 + wave * 16 + quad * 4;  // softmax state row = qi + r
    const int ntiles = bt + 1;
    #pragma unroll 1
    for (int t = 0; t < ntiles; t++) {
        const int j0 = t * 64;
        // ---- S = Q K^T (per wave: 16 x 64) ----
        f32x4 s[4] = {};
        #pragma unroll
        for (int nt = 0; nt < 4; nt++) {
            const unsigned short* kp = K + (size_t)(j0 + nt * 16 + l16) * 64 + quad * 8;
            short8 kf0 = *(const short8*)(kp);
            short8 kf1 = *(const short8*)(kp + 32);
            s[nt] = __builtin_amdgcn_mfma_f32_16x16x32_bf16(qf0, kf0, s[nt], 0, 0, 0);
            s[nt] = __builtin_amdgcn_mfma_f32_16x16x32_bf16(qf1, kf1, s[nt], 0, 0, 0);
        }
        // ---- scale + causal mask + reference's (==0 -> -inf) quirk ----
        float pm[4] = {-1e30f, -1e30f, -1e30f, -1e30f};
        #pragma unroll
        for (int nt = 0; nt < 4; nt++) {
            const int kj = j0 + nt * 16 + l16;
            #pragma unroll
            for (int r = 0; r < 4; r++) {
                float v = s[nt][r] * 0.125f;  // H^-0.5 = 1/8 exact
                v = (kj > qi + r || v == 0.0f) ? -1e30f : v;
                s[nt][r] = v;
                pm[r] = fmaxf(pm[r], v);
            }
        }
        // row-max across the 16 lanes sharing a quad
        #pragma unroll
        for (int off = 1; off < 16; off <<= 1)
            #pragma unroll
            for (int r = 0; r < 4; r++)
                pm[r] = fmaxf(pm[r], __shfl_xor(pm[r], off));
        float alpha[4];
        #pragma unroll
        for (int r = 0; r < 4; r++) {
            float mn = fmaxf(m_i[r], pm[r]);
            alpha[r] = __expf(m_i[r] - mn);   // first iter: exp(-1e30) = 0
            m_i[r] = mn;
        }
        // ---- P = exp(S - m), row-sum, stash P in LDS (C-layout -> A-layout) ----
        float ps[4] = {0.f, 0.f, 0.f, 0.f};
        #pragma unroll
        for (int nt = 0; nt < 4; nt++)
            #pragma unroll
            for (int r = 0; r < 4; r++) {
                float p = __expf(s[nt][r] - m_i[r]);
                ps[r] += p;
                p_lds[wave][quad * 4 + r][nt * 16 + l16] = f2bf(p);
            }
        #pragma unroll
        for (int off = 1; off < 16; off <<= 1)
            #pragma unroll
            for (int r = 0; r < 4; r++)
                ps[r] += __shfl_xor(ps[r], off);
        #pragma unroll
        for (int r = 0; r < 4; r++) l_i[r] = l_i[r] * alpha[r] + ps[r];
        #pragma unroll
        for (int ht = 0; ht < 4; ht++)
            #pragma unroll
            for (int r = 0; r < 4; r++)
                o[ht][r] *= alpha[r];
        __syncthreads();  // order this wave's P writes before its A-frag reads
        // ---- O += P V ----
        #pragma unroll
        for (int ks = 0; ks < 2; ks++) {
            short8 pf = *(const short8*)&p_lds[wave][l16][ks * 32 + quad * 8];
            #pragma unroll
            for (int ht = 0; ht < 4; ht++) {
                short8 vf = *(const short8*)(VT + (size_t)(ht * 16 + l16) * 2048 + j0 + ks * 32 + quad * 8);
                o[ht] = __builtin_amdgcn_mfma_f32_16x16x32_bf16(pf, vf, o[ht], 0, 0, 0);
            }
        }
        __syncthreads();  // protect P region before next iteration overwrites
    }
    // ---- epilogue: O / l ----
    float* op = out + ((size_t)b * 2048 + q0 + wave * 16 + quad * 4) * 64 + l16;
    #pragma unroll
    for (int r = 0; r < 4; r++) {
        float inv = 1.0f / l_i[r];
        #pragma unroll
        for (int ht = 0; ht < 4; ht++)
            op[r * 64 + ht * 16] = o[ht][r] * inv;
    }
}

// ---------------------------------------------------------------------------
extern "C" void kernel_launch(void* const* d_in, const int* in_sizes, int n_in,
                              void* d_out, int out_size, void* d_ws, size_t ws_size,
                              hipStream_t stream) {
    const float* x  = (const float*)d_in[0];
    const float* Wq = (const float*)d_in[1];
    const float* Wk = (const float*)d_in[2];
    const float* Wv = (const float*)d_in[3];
    float* out = (float*)d_out;
    unsigned short* ws = (unsigned short*)d_ws;
    unsigned short* wT = ws + 3 * NTOT;

    wtrans_kernel<<<dim3(3, 16), 256, 0, stream>>>(Wq, Wk, Wv, wT);
    proj_kernel<<<dim3(128, 3), 256, 0, stream>>>(x, wT, ws);
    attn_kernel<<<dim3(32, 4), 256, 0, stream>>>(ws, out);
}

// Round 2
// 164.848 us; speedup vs baseline: 1.4156x; 1.4156x over previous
//
#include <hip/hip_runtime.h>

// B=4, T=2048, C=1024, H=64. fp32 in/out, bf16 MFMA internally.
// ws layout:
//   u16 region (offsets in u16 elements):
//     [0,        524288)  q  bf16  [b*2048+t][64]
//     [524288,  1048576)  k  bf16  [b*2048+t][64]
//     [1048576, 1572864)  vT bf16  [b][h][t]   (b*131072 + h*2048 + t)
//     [1572864, 1769472)  wT bf16  [sel][h][c] (sel*65536 + h*1024 + c)
//   fp32 region at byte offset 3538944:
//     Opart [4*S][64][64]  unnormalized partial O per (b, q-tile, k-chunk)
//     MLpart[4*S][2][64]   row max m / row sum l
// S = slots per batch = ct*a*(a+1)/2 with a = 32/ct (ct = k-tiles per chunk).

typedef __attribute__((ext_vector_type(8))) short short8;
typedef __attribute__((ext_vector_type(4))) float f32x4;

#define NTOT 524288   // 8192*64
#define WT_OFF (3 * NTOT)          // 1572864
#define BASE_BYTES 3538944

__device__ __forceinline__ unsigned short f2bf(float f) {
    unsigned int u = __builtin_bit_cast(unsigned int, f);
    return (unsigned short)((u + 0x7fffu + ((u >> 16) & 1u)) >> 16);
}

__device__ __forceinline__ short8 pack8(float4 a, float4 b) {
    short8 r;
    r[0] = (short)f2bf(a.x); r[1] = (short)f2bf(a.y);
    r[2] = (short)f2bf(a.z); r[3] = (short)f2bf(a.w);
    r[4] = (short)f2bf(b.x); r[5] = (short)f2bf(b.y);
    r[6] = (short)f2bf(b.z); r[7] = (short)f2bf(b.w);
    return r;
}

// ---------------------------------------------------------------------------
// Kernel 1: transpose W (fp32 [1024][64]) -> wT bf16 [64][1024], x3 matrices
// ---------------------------------------------------------------------------
__global__ __launch_bounds__(256) void wtrans_kernel(
    const float* __restrict__ Wq, const float* __restrict__ Wk,
    const float* __restrict__ Wv, unsigned short* __restrict__ wt)
{
    const int sel = blockIdx.x;
    const int c0  = blockIdx.y * 64;
    const float* W = (sel == 0) ? Wq : ((sel == 1) ? Wk : Wv);
    __shared__ unsigned short tile[64][72];
    const int tid = threadIdx.x;
    {
        const int c  = tid >> 2;
        const int hg = (tid & 3) * 16;
        const float* src = W + (size_t)(c0 + c) * 64 + hg;
        #pragma unroll
        for (int i = 0; i < 16; i++) tile[c][hg + i] = f2bf(src[i]);
    }
    __syncthreads();
    {
        const int h  = tid >> 2;
        const int cg = (tid & 3) * 16;
        unsigned short* dst = wt + ((size_t)sel * 64 + h) * 1024 + c0 + cg;
        #pragma unroll
        for (int i = 0; i < 16; i++) dst[i] = tile[cg + i][h];
    }
}

// ---------------------------------------------------------------------------
// Kernel 2: fused projections. One wave per block, 16 t-rows. Reads x once,
// computes q[t][h], k[t][h] (A = x, B = wT) and vT[h][t] (A = wTv, B = x;
// same x fragment serves both A and B roles). grid = 512, block = 64.
// ---------------------------------------------------------------------------
__global__ __launch_bounds__(64) void proj_fused_kernel(
    const float* __restrict__ x, const unsigned short* __restrict__ wt,
    unsigned short* __restrict__ ws)
{
    const int m0   = blockIdx.x * 16;
    const int lane = threadIdx.x & 63;
    const int quad = lane >> 4, l16 = lane & 15;

    const unsigned short* wq = wt;
    const unsigned short* wk = wt + 65536;
    const unsigned short* wv = wt + 131072;

    f32x4 aq[4] = {}, ak[4] = {}, av[4] = {};

    const float* xrow = x + (size_t)(m0 + l16) * 1024 + quad * 8;
    float4 xa = *(const float4*)(xrow);
    float4 xb = *(const float4*)(xrow + 4);
    for (int kk = 0; kk < 1024; kk += 32) {
        const int nk = (kk + 32) & 1023;   // wraps to 0 on last iter (unused)
        float4 na = *(const float4*)(xrow + nk);
        float4 nb = *(const float4*)(xrow + nk + 4);
        short8 af = pack8(xa, xb);
        const int wo = kk + quad * 8;
        #pragma unroll
        for (int nt = 0; nt < 4; nt++) {
            const size_t ro = (size_t)(nt * 16 + l16) * 1024 + wo;
            short8 bq = *(const short8*)(wq + ro);
            short8 bk = *(const short8*)(wk + ro);
            short8 bv = *(const short8*)(wv + ro);
            aq[nt] = __builtin_amdgcn_mfma_f32_16x16x32_bf16(af, bq, aq[nt], 0, 0, 0);
            ak[nt] = __builtin_amdgcn_mfma_f32_16x16x32_bf16(af, bk, ak[nt], 0, 0, 0);
            av[nt] = __builtin_amdgcn_mfma_f32_16x16x32_bf16(bv, af, av[nt], 0, 0, 0);
        }
        xa = na; xb = nb;
    }
    // q/k: D row = t = m0 + quad*4 + r, col = h = nt*16 + l16
    unsigned short* qdst = ws;
    unsigned short* kdst = ws + NTOT;
    const int mo = m0 + quad * 4;
    #pragma unroll
    for (int nt = 0; nt < 4; nt++)
        #pragma unroll
        for (int r = 0; r < 4; r++) {
            qdst[(size_t)(mo + r) * 64 + nt * 16 + l16] = f2bf(aq[nt][r]);
            kdst[(size_t)(mo + r) * 64 + nt * 16 + l16] = f2bf(ak[nt][r]);
        }
    // vT: D row = h = nt*16 + quad*4 + r, col = t = m0 + l16
    const int b = m0 >> 11;
    const int tb = (m0 & 2047) + l16;
    unsigned short* vdst = ws + 2 * NTOT + (size_t)b * 131072;
    #pragma unroll
    for (int nt = 0; nt < 4; nt++)
        #pragma unroll
        for (int r = 0; r < 4; r++)
            vdst[(size_t)(nt * 16 + quad * 4 + r) * 2048 + tb] = f2bf(av[nt][r]);
}

// ---------------------------------------------------------------------------
// Kernel 3a: split-K flash attention partials. Block = 64 q-rows x one
// k-chunk of `ct` 64-wide tiles. grid = (32, 32/ct, 4). No __syncthreads:
// p_lds is strictly per-wave.
// ---------------------------------------------------------------------------
__global__ __launch_bounds__(256) void attn_partial_kernel(
    const unsigned short* __restrict__ ws, float* __restrict__ Opart,
    float* __restrict__ MLpart, int ct, int S)
{
    const int qt = blockIdx.x;
    const int c  = blockIdx.y;
    const int b  = blockIdx.z;
    if (c * ct > qt) return;

    const int q0 = qt * 64;
    const int tid  = threadIdx.x;
    const int wave = tid >> 6, lane = tid & 63;
    const int quad = lane >> 4, l16 = lane & 15;

    const unsigned short* Q  = ws + (size_t)b * 131072;
    const unsigned short* K  = ws + NTOT + (size_t)b * 131072;
    const unsigned short* VT = ws + 2 * NTOT + (size_t)b * 131072;

    __shared__ unsigned short p_lds[4][16][72];

    const int qrow = q0 + wave * 16 + l16;
    short8 qf0 = *(const short8*)(Q + (size_t)qrow * 64 + quad * 8);
    short8 qf1 = *(const short8*)(Q + (size_t)qrow * 64 + 32 + quad * 8);

    f32x4 o[4] = {};
    float m_i[4], l_i[4];
    #pragma unroll
    for (int r = 0; r < 4; r++) { m_i[r] = -1e30f; l_i[r] = 0.f; }

    const int qi = q0 + wave * 16 + quad * 4;
    const int t0 = c * ct;
    const int t1 = min(t0 + ct - 1, qt);
    for (int t = t0; t <= t1; t++) {
        const int j0 = t * 64;
        f32x4 s[4] = {};
        #pragma unroll
        for (int nt = 0; nt < 4; nt++) {
            const unsigned short* kp = K + (size_t)(j0 + nt * 16 + l16) * 64 + quad * 8;
            short8 kf0 = *(const short8*)(kp);
            short8 kf1 = *(const short8*)(kp + 32);
            s[nt] = __builtin_amdgcn_mfma_f32_16x16x32_bf16(qf0, kf0, s[nt], 0, 0, 0);
            s[nt] = __builtin_amdgcn_mfma_f32_16x16x32_bf16(qf1, kf1, s[nt], 0, 0, 0);
        }
        float pm[4] = {-1e30f, -1e30f, -1e30f, -1e30f};
        #pragma unroll
        for (int nt = 0; nt < 4; nt++) {
            const int kj = j0 + nt * 16 + l16;
            #pragma unroll
            for (int r = 0; r < 4; r++) {
                float v = s[nt][r] * 0.125f;
                v = (kj > qi + r || v == 0.0f) ? -1e30f : v;  // causal + ==0 quirk
                s[nt][r] = v;
                pm[r] = fmaxf(pm[r], v);
            }
        }
        #pragma unroll
        for (int off = 1; off < 16; off <<= 1)
            #pragma unroll
            for (int r = 0; r < 4; r++)
                pm[r] = fmaxf(pm[r], __shfl_xor(pm[r], off));
        float alpha[4];
        #pragma unroll
        for (int r = 0; r < 4; r++) {
            float mn = fmaxf(m_i[r], pm[r]);
            alpha[r] = __expf(m_i[r] - mn);
            m_i[r] = mn;
        }
        float ps[4] = {0.f, 0.f, 0.f, 0.f};
        #pragma unroll
        for (int nt = 0; nt < 4; nt++)
            #pragma unroll
            for (int r = 0; r < 4; r++) {
                float p = __expf(s[nt][r] - m_i[r]);
                ps[r] += p;
                p_lds[wave][quad * 4 + r][nt * 16 + l16] = f2bf(p);
            }
        #pragma unroll
        for (int off = 1; off < 16; off <<= 1)
            #pragma unroll
            for (int r = 0; r < 4; r++)
                ps[r] += __shfl_xor(ps[r], off);
        #pragma unroll
        for (int r = 0; r < 4; r++) l_i[r] = l_i[r] * alpha[r] + ps[r];
        #pragma unroll
        for (int ht = 0; ht < 4; ht++)
            #pragma unroll
            for (int r = 0; r < 4; r++)
                o[ht][r] *= alpha[r];
        #pragma unroll
        for (int ks = 0; ks < 2; ks++) {
            short8 pf = *(const short8*)&p_lds[wave][l16][ks * 32 + quad * 8];
            #pragma unroll
            for (int ht = 0; ht < 4; ht++) {
                short8 vf = *(const short8*)(VT + (size_t)(ht * 16 + l16) * 2048 + j0 + ks * 32 + quad * 8);
                o[ht] = __builtin_amdgcn_mfma_f32_16x16x32_bf16(pf, vf, o[ht], 0, 0, 0);
            }
        }
    }
    // ---- write partials (unnormalized O, m, l) ----
    const int a = qt / ct, rr = qt - a * ct;
    const int slot = b * S + ct * a * (a + 1) / 2 + rr * (a + 1) + c;
    float* Os = Opart + (size_t)slot * 4096;
    const int row0 = wave * 16 + quad * 4;
    #pragma unroll
    for (int ht = 0; ht < 4; ht++)
        #pragma unroll
        for (int r = 0; r < 4; r++)
            Os[(size_t)(row0 + r) * 64 + ht * 16 + l16] = o[ht][r];
    if (l16 == 0) {
        float* Ms = MLpart + (size_t)slot * 128;
        #pragma unroll
        for (int r = 0; r < 4; r++) {
            Ms[row0 + r]      = m_i[r];
            Ms[64 + row0 + r] = l_i[r];
        }
    }
}

// ---------------------------------------------------------------------------
// Kernel 3b: combine partials. grid = (32, 4), block = 256.
// thread -> (row = tid>>2, 16-col group = (tid&3)*16).
// ---------------------------------------------------------------------------
__global__ __launch_bounds__(256) void attn_combine_kernel(
    const float* __restrict__ Opart, const float* __restrict__ MLpart,
    float* __restrict__ out, int ct, int S)
{
    const int qt = blockIdx.x;
    const int b  = blockIdx.y;
    const int nc = qt / ct + 1;
    const int a = qt / ct, rr = qt - a * ct;
    const int slot0 = b * S + ct * a * (a + 1) / 2 + rr * (a + 1);

    const int row  = threadIdx.x >> 2;
    const int colg = (threadIdx.x & 3) * 16;

    float M = -1e30f;
    for (int s = 0; s < nc; s++)
        M = fmaxf(M, MLpart[(size_t)(slot0 + s) * 128 + row]);
    float l = 0.f;
    f32x4 o0 = {}, o1 = {}, o2 = {}, o3 = {};
    for (int s = 0; s < nc; s++) {
        const size_t base = (size_t)(slot0 + s);
        const float w = __expf(MLpart[base * 128 + row] - M);
        l += w * MLpart[base * 128 + 64 + row];
        const f32x4* Op = (const f32x4*)(Opart + base * 4096 + (size_t)row * 64 + colg);
        o0 += w * Op[0]; o1 += w * Op[1]; o2 += w * Op[2]; o3 += w * Op[3];
    }
    const float inv = 1.0f / l;
    f32x4* dst = (f32x4*)(out + ((size_t)b * 2048 + qt * 64 + row) * 64 + colg);
    dst[0] = o0 * inv; dst[1] = o1 * inv; dst[2] = o2 * inv; dst[3] = o3 * inv;
}

// ---------------------------------------------------------------------------
// Fallback: original single-pass attention (used only if ws too small).
// ---------------------------------------------------------------------------
__global__ __launch_bounds__(256) void attn_mono_kernel(
    const unsigned short* __restrict__ ws, float* __restrict__ out)
{
    const int b  = blockIdx.y;
    const int bt = blockIdx.x;
    const int q0 = bt * 64;
    const int tid  = threadIdx.x;
    const int wave = tid >> 6, lane = tid & 63;
    const int quad = lane >> 4, l16 = lane & 15;

    const unsigned short* Q  = ws + (size_t)b * 131072;
    const unsigned short* K  = ws + NTOT + (size_t)b * 131072;
    const unsigned short* VT = ws + 2 * NTOT + (size_t)b * 131072;

    __shared__ unsigned short p_lds[4][16][72];

    const int qrow = q0 + wave * 16 + l16;
    short8 qf0 = *(const short8*)(Q + (size_t)qrow * 64 + quad * 8);
    short8 qf1 = *(const short8*)(Q + (size_t)qrow * 64 + 32 + quad * 8);

    f32x4 o[4] = {};
    float m_i[4], l_i[4];
    #pragma unroll
    for (int r = 0; r < 4; r++) { m_i[r] = -1e30f; l_i[r] = 0.f; }
    const int qi = q0 + wave * 16 + quad * 4;
    for (int t = 0; t <= bt; t++) {
        const int j0 = t * 64;
        f32x4 s[4] = {};
        #pragma unroll
        for (int nt = 0; nt < 4; nt++) {
            const unsigned short* kp = K + (size_t)(j0 + nt * 16 + l16) * 64 + quad * 8;
            short8 kf0 = *(const short8*)(kp);
            short8 kf1 = *(const short8*)(kp + 32);
            s[nt] = __builtin_amdgcn_mfma_f32_16x16x32_bf16(qf0, kf0, s[nt], 0, 0, 0);
            s[nt] = __builtin_amdgcn_mfma_f32_16x16x32_bf16(qf1, kf1, s[nt], 0, 0, 0);
        }
        float pm[4] = {-1e30f, -1e30f, -1e30f, -1e30f};
        #pragma unroll
        for (int nt = 0; nt < 4; nt++) {
            const int kj = j0 + nt * 16 + l16;
            #pragma unroll
            for (int r = 0; r < 4; r++) {
                float v = s[nt][r] * 0.125f;
                v = (kj > qi + r || v == 0.0f) ? -1e30f : v;
                s[nt][r] = v;
                pm[r] = fmaxf(pm[r], v);
            }
        }
        #pragma unroll
        for (int off = 1; off < 16; off <<= 1)
            #pragma unroll
            for (int r = 0; r < 4; r++)
                pm[r] = fmaxf(pm[r], __shfl_xor(pm[r], off));
        float alpha[4];
        #pragma unroll
        for (int r = 0; r < 4; r++) {
            float mn = fmaxf(m_i[r], pm[r]);
            alpha[r] = __expf(m_i[r] - mn);
            m_i[r] = mn;
        }
        float ps[4] = {0.f, 0.f, 0.f, 0.f};
        #pragma unroll
        for (int nt = 0; nt < 4; nt++)
            #pragma unroll
            for (int r = 0; r < 4; r++) {
                float p = __expf(s[nt][r] - m_i[r]);
                ps[r] += p;
                p_lds[wave][quad * 4 + r][nt * 16 + l16] = f2bf(p);
            }
        #pragma unroll
        for (int off = 1; off < 16; off <<= 1)
            #pragma unroll
            for (int r = 0; r < 4; r++)
                ps[r] += __shfl_xor(ps[r], off);
        #pragma unroll
        for (int r = 0; r < 4; r++) l_i[r] = l_i[r] * alpha[r] + ps[r];
        #pragma unroll
        for (int ht = 0; ht < 4; ht++)
            #pragma unroll
            for (int r = 0; r < 4; r++)
                o[ht][r] *= alpha[r];
        #pragma unroll
        for (int ks = 0; ks < 2; ks++) {
            short8 pf = *(const short8*)&p_lds[wave][l16][ks * 32 + quad * 8];
            #pragma unroll
            for (int ht = 0; ht < 4; ht++) {
                short8 vf = *(const short8*)(VT + (size_t)(ht * 16 + l16) * 2048 + j0 + ks * 32 + quad * 8);
                o[ht] = __builtin_amdgcn_mfma_f32_16x16x32_bf16(pf, vf, o[ht], 0, 0, 0);
            }
        }
    }
    float* op = out + ((size_t)b * 2048 + q0 + wave * 16 + quad * 4) * 64 + l16;
    #pragma unroll
    for (int r = 0; r < 4; r++) {
        float inv = 1.0f / l_i[r];
        #pragma unroll
        for (int ht = 0; ht < 4; ht++)
            op[r * 64 + ht * 16] = o[ht][r] * inv;
    }
}

// ---------------------------------------------------------------------------
extern "C" void kernel_launch(void* const* d_in, const int* in_sizes, int n_in,
                              void* d_out, int out_size, void* d_ws, size_t ws_size,
                              hipStream_t stream) {
    const float* x  = (const float*)d_in[0];
    const float* Wq = (const float*)d_in[1];
    const float* Wk = (const float*)d_in[2];
    const float* Wv = (const float*)d_in[3];
    float* out = (float*)d_out;
    unsigned short* ws = (unsigned short*)d_ws;
    unsigned short* wT = ws + WT_OFF;

    wtrans_kernel<<<dim3(3, 16), 256, 0, stream>>>(Wq, Wk, Wv, wT);
    proj_fused_kernel<<<dim3(512), 64, 0, stream>>>(x, wT, ws);

    // pick finest chunk size that fits in the workspace
    int ct = 0, S = 0;
    const int cands[5] = {2, 4, 8, 16, 32};
    for (int i = 0; i < 5; i++) {
        const int cc = cands[i];
        const int aa = 32 / cc;
        const int ss = cc * aa * (aa + 1) / 2;          // slots per batch
        const size_t need = (size_t)BASE_BYTES + (size_t)4 * ss * (4096 + 128) * 4;
        if (need <= ws_size) { ct = cc; S = ss; break; }
    }
    if (ct) {
        float* Opart  = (float*)((char*)d_ws + BASE_BYTES);
        float* MLpart = Opart + (size_t)4 * S * 4096;
        attn_partial_kernel<<<dim3(32, 32 / ct, 4), 256, 0, stream>>>(ws, Opart, MLpart, ct, S);
        attn_combine_kernel<<<dim3(32, 4), 256, 0, stream>>>(Opart, MLpart, out, ct, S);
    } else {
        attn_mono_kernel<<<dim3(32, 4), 256, 0, stream>>>(ws, out);
    }
}

// Round 4
// 146.873 us; speedup vs baseline: 1.5889x; 1.1224x over previous
//
#include <hip/hip_runtime.h>

// B=4, T=2048, C=1024, H=64. fp32 in/out, bf16 MFMA internally.
// ws layout:
//   u16 region (offsets in u16 elements):
//     [0,        524288)  q  bf16  [b*2048+t][64]
//     [524288,  1048576)  k  bf16  [b*2048+t][64]
//     [1048576, 1572864)  vT bf16  [b][h][t]   (b*131072 + h*2048 + t)
//     [1572864, 1769472)  wT bf16  [sel][h][c] (sel*65536 + h*1024 + c)
//   fp32 region at byte offset 3538944:
//     Opart [4*S][64][64]  unnormalized partial O per (b, q-tile, k-chunk)
//     MLpart[4*S][2][64]   row max m / row sum l

typedef __attribute__((ext_vector_type(8))) short short8;
typedef __attribute__((ext_vector_type(4))) float f32x4;

#define NTOT 524288   // 8192*64
#define WT_OFF (3 * NTOT)
#define BASE_BYTES 3538944

__device__ __forceinline__ unsigned short f2bf(float f) {
    unsigned int u = __builtin_bit_cast(unsigned int, f);
    return (unsigned short)((u + 0x7fffu + ((u >> 16) & 1u)) >> 16);
}

__device__ __forceinline__ short8 pack8(float4 a, float4 b) {
    short8 r;
    r[0] = (short)f2bf(a.x); r[1] = (short)f2bf(a.y);
    r[2] = (short)f2bf(a.z); r[3] = (short)f2bf(a.w);
    r[4] = (short)f2bf(b.x); r[5] = (short)f2bf(b.y);
    r[6] = (short)f2bf(b.z); r[7] = (short)f2bf(b.w);
    return r;
}

// ---------------------------------------------------------------------------
// Kernel 1: transpose W (fp32 [1024][64]) -> wT bf16 [64][1024], x3 matrices
// ---------------------------------------------------------------------------
__global__ __launch_bounds__(256) void wtrans_kernel(
    const float* __restrict__ Wq, const float* __restrict__ Wk,
    const float* __restrict__ Wv, unsigned short* __restrict__ wt)
{
    const int sel = blockIdx.x;
    const int c0  = blockIdx.y * 64;
    const float* W = (sel == 0) ? Wq : ((sel == 1) ? Wk : Wv);
    __shared__ unsigned short tile[64][72];
    const int tid = threadIdx.x;
    {
        const int c  = tid >> 2;
        const int hg = (tid & 3) * 16;
        const float* src = W + (size_t)(c0 + c) * 64 + hg;
        #pragma unroll
        for (int i = 0; i < 16; i++) tile[c][hg + i] = f2bf(src[i]);
    }
    __syncthreads();
    {
        const int h  = tid >> 2;
        const int cg = (tid & 3) * 16;
        unsigned short* dst = wt + ((size_t)sel * 64 + h) * 1024 + c0 + cg;
        #pragma unroll
        for (int i = 0; i < 16; i++) dst[i] = tile[cg + i][h];
    }
}

// ---------------------------------------------------------------------------
// Kernel 2: fused projections, cross-wave split-K, SCALAR reduction path.
// Block = 256 threads = 4 waves over the same 16 t-rows; wave w accumulates
// K in [w*256, (w+1)*256) (8 MFMA iterations). Partials go to LDS as scalar
// floats (padded strides), reduced after one __syncthreads, stored as
// scalar bf16 (the store style that passed in rounds 1-2).
// grid = 512 -> 2048 waves, 2 blocks/CU.
// ---------------------------------------------------------------------------
__global__ __launch_bounds__(256) void proj_fused_kernel(
    const float* __restrict__ x, const unsigned short* __restrict__ wt,
    unsigned short* __restrict__ ws)
{
    const int m0   = blockIdx.x * 16;
    const int tid  = threadIdx.x;
    const int wave = tid >> 6, lane = tid & 63;
    const int quad = lane >> 4, l16 = lane & 15;

    const unsigned short* wq = wt;
    const unsigned short* wk = wt + 65536;
    const unsigned short* wv = wt + 131072;

    __shared__ float redq[4][16][65];   // [wave][t][h]
    __shared__ float redk[4][16][65];   // [wave][t][h]
    __shared__ float redv[4][64][17];   // [wave][h][t]

    f32x4 aq[4] = {}, ak[4] = {}, av[4] = {};

    const int kbase = wave * 256;
    const float* xrow = x + (size_t)(m0 + l16) * 1024 + kbase + quad * 8;
    float4 xa = *(const float4*)(xrow);
    float4 xb = *(const float4*)(xrow + 4);
    for (int kk = 0; kk < 256; kk += 32) {
        const int nk = (kk + 32) & 255;     // wraps on last iter (unused)
        float4 na = *(const float4*)(xrow + nk);
        float4 nb = *(const float4*)(xrow + nk + 4);
        short8 af = pack8(xa, xb);
        const int wo = kbase + kk + quad * 8;
        #pragma unroll
        for (int nt = 0; nt < 4; nt++) {
            const size_t ro = (size_t)(nt * 16 + l16) * 1024 + wo;
            short8 bq = *(const short8*)(wq + ro);
            short8 bk = *(const short8*)(wk + ro);
            short8 bv = *(const short8*)(wv + ro);
            aq[nt] = __builtin_amdgcn_mfma_f32_16x16x32_bf16(af, bq, aq[nt], 0, 0, 0);
            ak[nt] = __builtin_amdgcn_mfma_f32_16x16x32_bf16(af, bk, ak[nt], 0, 0, 0);
            av[nt] = __builtin_amdgcn_mfma_f32_16x16x32_bf16(bv, af, av[nt], 0, 0, 0);
        }
        xa = na; xb = nb;
    }
    // scalar stash: q/k rows t=quad*4+r, cols h=nt*16+l16; v rows h, cols t=l16
    #pragma unroll
    for (int nt = 0; nt < 4; nt++)
        #pragma unroll
        for (int r = 0; r < 4; r++) {
            redq[wave][quad * 4 + r][nt * 16 + l16] = aq[nt][r];
            redk[wave][quad * 4 + r][nt * 16 + l16] = ak[nt][r];
            redv[wave][nt * 16 + quad * 4 + r][l16] = av[nt][r];
        }
    __syncthreads();

    const int b   = m0 >> 11;
    const int tb0 = m0 & 2047;
    {   // q/k: thread -> (row = tid>>4, h0 = (tid&15)*4), 4 scalar elems each
        const int row = tid >> 4, h0 = (tid & 15) * 4;
        #pragma unroll
        for (int i = 0; i < 4; i++) {
            const int h = h0 + i;
            float sq = redq[0][row][h] + redq[1][row][h]
                     + redq[2][row][h] + redq[3][row][h];
            float sk = redk[0][row][h] + redk[1][row][h]
                     + redk[2][row][h] + redk[3][row][h];
            ws[       (size_t)(m0 + row) * 64 + h] = f2bf(sq);
            ws[NTOT + (size_t)(m0 + row) * 64 + h] = f2bf(sk);
        }
    }
    {   // vT: thread -> (h = tid>>2, t4 = (tid&3)*4), 4 scalar elems each
        const int h = tid >> 2, t4 = (tid & 3) * 4;
        unsigned short* vdst = ws + 2 * NTOT + (size_t)b * 131072
                             + (size_t)h * 2048 + tb0;
        #pragma unroll
        for (int i = 0; i < 4; i++) {
            const int t = t4 + i;
            float sv = redv[0][h][t] + redv[1][h][t]
                     + redv[2][h][t] + redv[3][h][t];
            vdst[t] = f2bf(sv);
        }
    }
}

// ---------------------------------------------------------------------------
// Kernel 3a: split-K flash attention partials. Block = 64 q-rows x one
// k-chunk of `ct` 64-wide tiles. grid = (32, 32/ct, 4).
// ---------------------------------------------------------------------------
__global__ __launch_bounds__(256) void attn_partial_kernel(
    const unsigned short* __restrict__ ws, float* __restrict__ Opart,
    float* __restrict__ MLpart, int ct, int S)
{
    const int qt = blockIdx.x;
    const int c  = blockIdx.y;
    const int b  = blockIdx.z;
    if (c * ct > qt) return;

    const int q0 = qt * 64;
    const int tid  = threadIdx.x;
    const int wave = tid >> 6, lane = tid & 63;
    const int quad = lane >> 4, l16 = lane & 15;

    const unsigned short* Q  = ws + (size_t)b * 131072;
    const unsigned short* K  = ws + NTOT + (size_t)b * 131072;
    const unsigned short* VT = ws + 2 * NTOT + (size_t)b * 131072;

    __shared__ unsigned short p_lds[4][16][72];

    const int qrow = q0 + wave * 16 + l16;
    short8 qf0 = *(const short8*)(Q + (size_t)qrow * 64 + quad * 8);
    short8 qf1 = *(const short8*)(Q + (size_t)qrow * 64 + 32 + quad * 8);

    f32x4 o[4] = {};
    float m_i[4], l_i[4];
    #pragma unroll
    for (int r = 0; r < 4; r++) { m_i[r] = -1e30f; l_i[r] = 0.f; }

    const int qi = q0 + wave * 16 + quad * 4;
    const int t0 = c * ct;
    const int t1 = min(t0 + ct - 1, qt);
    for (int t = t0; t <= t1; t++) {
        const int j0 = t * 64;
        f32x4 s[4] = {};
        #pragma unroll
        for (int nt = 0; nt < 4; nt++) {
            const unsigned short* kp = K + (size_t)(j0 + nt * 16 + l16) * 64 + quad * 8;
            short8 kf0 = *(const short8*)(kp);
            short8 kf1 = *(const short8*)(kp + 32);
            s[nt] = __builtin_amdgcn_mfma_f32_16x16x32_bf16(qf0, kf0, s[nt], 0, 0, 0);
            s[nt] = __builtin_amdgcn_mfma_f32_16x16x32_bf16(qf1, kf1, s[nt], 0, 0, 0);
        }
        float pm[4] = {-1e30f, -1e30f, -1e30f, -1e30f};
        #pragma unroll
        for (int nt = 0; nt < 4; nt++) {
            const int kj = j0 + nt * 16 + l16;
            #pragma unroll
            for (int r = 0; r < 4; r++) {
                float v = s[nt][r] * 0.125f;
                v = (kj > qi + r || v == 0.0f) ? -1e30f : v;  // causal + ==0 quirk
                s[nt][r] = v;
                pm[r] = fmaxf(pm[r], v);
            }
        }
        #pragma unroll
        for (int off = 1; off < 16; off <<= 1)
            #pragma unroll
            for (int r = 0; r < 4; r++)
                pm[r] = fmaxf(pm[r], __shfl_xor(pm[r], off));
        float alpha[4];
        #pragma unroll
        for (int r = 0; r < 4; r++) {
            float mn = fmaxf(m_i[r], pm[r]);
            alpha[r] = __expf(m_i[r] - mn);
            m_i[r] = mn;
        }
        float ps[4] = {0.f, 0.f, 0.f, 0.f};
        #pragma unroll
        for (int nt = 0; nt < 4; nt++)
            #pragma unroll
            for (int r = 0; r < 4; r++) {
                float p = __expf(s[nt][r] - m_i[r]);
                ps[r] += p;
                p_lds[wave][quad * 4 + r][nt * 16 + l16] = f2bf(p);
            }
        #pragma unroll
        for (int off = 1; off < 16; off <<= 1)
            #pragma unroll
            for (int r = 0; r < 4; r++)
                ps[r] += __shfl_xor(ps[r], off);
        #pragma unroll
        for (int r = 0; r < 4; r++) l_i[r] = l_i[r] * alpha[r] + ps[r];
        #pragma unroll
        for (int ht = 0; ht < 4; ht++)
            #pragma unroll
            for (int r = 0; r < 4; r++)
                o[ht][r] *= alpha[r];
        #pragma unroll
        for (int ks = 0; ks < 2; ks++) {
            short8 pf = *(const short8*)&p_lds[wave][l16][ks * 32 + quad * 8];
            #pragma unroll
            for (int ht = 0; ht < 4; ht++) {
                short8 vf = *(const short8*)(VT + (size_t)(ht * 16 + l16) * 2048 + j0 + ks * 32 + quad * 8);
                o[ht] = __builtin_amdgcn_mfma_f32_16x16x32_bf16(pf, vf, o[ht], 0, 0, 0);
            }
        }
    }
    const int a = qt / ct, rr = qt - a * ct;
    const int slot = b * S + ct * a * (a + 1) / 2 + rr * (a + 1) + c;
    float* Os = Opart + (size_t)slot * 4096;
    const int row0 = wave * 16 + quad * 4;
    #pragma unroll
    for (int ht = 0; ht < 4; ht++)
        #pragma unroll
        for (int r = 0; r < 4; r++)
            Os[(size_t)(row0 + r) * 64 + ht * 16 + l16] = o[ht][r];
    if (l16 == 0) {
        float* Ms = MLpart + (size_t)slot * 128;
        #pragma unroll
        for (int r = 0; r < 4; r++) {
            Ms[row0 + r]      = m_i[r];
            Ms[64 + row0 + r] = l_i[r];
        }
    }
}

// ---------------------------------------------------------------------------
// Kernel 3b: combine partials. grid = (32, 4), block = 256.
// ---------------------------------------------------------------------------
__global__ __launch_bounds__(256) void attn_combine_kernel(
    const float* __restrict__ Opart, const float* __restrict__ MLpart,
    float* __restrict__ out, int ct, int S)
{
    const int qt = blockIdx.x;
    const int b  = blockIdx.y;
    const int nc = qt / ct + 1;
    const int a = qt / ct, rr = qt - a * ct;
    const int slot0 = b * S + ct * a * (a + 1) / 2 + rr * (a + 1);

    const int row  = threadIdx.x >> 2;
    const int colg = (threadIdx.x & 3) * 16;

    float M = -1e30f;
    for (int s = 0; s < nc; s++)
        M = fmaxf(M, MLpart[(size_t)(slot0 + s) * 128 + row]);
    float l = 0.f;
    f32x4 o0 = {}, o1 = {}, o2 = {}, o3 = {};
    for (int s = 0; s < nc; s++) {
        const size_t base = (size_t)(slot0 + s);
        const float w = __expf(MLpart[base * 128 + row] - M);
        l += w * MLpart[base * 128 + 64 + row];
        const f32x4* Op = (const f32x4*)(Opart + base * 4096 + (size_t)row * 64 + colg);
        o0 += w * Op[0]; o1 += w * Op[1]; o2 += w * Op[2]; o3 += w * Op[3];
    }
    const float inv = 1.0f / l;
    f32x4* dst = (f32x4*)(out + ((size_t)b * 2048 + qt * 64 + row) * 64 + colg);
    dst[0] = o0 * inv; dst[1] = o1 * inv; dst[2] = o2 * inv; dst[3] = o3 * inv;
}

// ---------------------------------------------------------------------------
// Fallback: single-pass attention (used only if ws too small for partials).
// ---------------------------------------------------------------------------
__global__ __launch_bounds__(256) void attn_mono_kernel(
    const unsigned short* __restrict__ ws, float* __restrict__ out)
{
    const int b  = blockIdx.y;
    const int bt = blockIdx.x;
    const int q0 = bt * 64;
    const int tid  = threadIdx.x;
    const int wave = tid >> 6, lane = tid & 63;
    const int quad = lane >> 4, l16 = lane & 15;

    const unsigned short* Q  = ws + (size_t)b * 131072;
    const unsigned short* K  = ws + NTOT + (size_t)b * 131072;
    const unsigned short* VT = ws + 2 * NTOT + (size_t)b * 131072;

    __shared__ unsigned short p_lds[4][16][72];

    const int qrow = q0 + wave * 16 + l16;
    short8 qf0 = *(const short8*)(Q + (size_t)qrow * 64 + quad * 8);
    short8 qf1 = *(const short8*)(Q + (size_t)qrow * 64 + 32 + quad * 8);

    f32x4 o[4] = {};
    float m_i[4], l_i[4];
    #pragma unroll
    for (int r = 0; r < 4; r++) { m_i[r] = -1e30f; l_i[r] = 0.f; }
    const int qi = q0 + wave * 16 + quad * 4;
    for (int t = 0; t <= bt; t++) {
        const int j0 = t * 64;
        f32x4 s[4] = {};
        #pragma unroll
        for (int nt = 0; nt < 4; nt++) {
            const unsigned short* kp = K + (size_t)(j0 + nt * 16 + l16) * 64 + quad * 8;
            short8 kf0 = *(const short8*)(kp);
            short8 kf1 = *(const short8*)(kp + 32);
            s[nt] = __builtin_amdgcn_mfma_f32_16x16x32_bf16(qf0, kf0, s[nt], 0, 0, 0);
            s[nt] = __builtin_amdgcn_mfma_f32_16x16x32_bf16(qf1, kf1, s[nt], 0, 0, 0);
        }
        float pm[4] = {-1e30f, -1e30f, -1e30f, -1e30f};
        #pragma unroll
        for (int nt = 0; nt < 4; nt++) {
            const int kj = j0 + nt * 16 + l16;
            #pragma unroll
            for (int r = 0; r < 4; r++) {
                float v = s[nt][r] * 0.125f;
                v = (kj > qi + r || v == 0.0f) ? -1e30f : v;
                s[nt][r] = v;
                pm[r] = fmaxf(pm[r], v);
            }
        }
        #pragma unroll
        for (int off = 1; off < 16; off <<= 1)
            #pragma unroll
            for (int r = 0; r < 4; r++)
                pm[r] = fmaxf(pm[r], __shfl_xor(pm[r], off));
        float alpha[4];
        #pragma unroll
        for (int r = 0; r < 4; r++) {
            float mn = fmaxf(m_i[r], pm[r]);
            alpha[r] = __expf(m_i[r] - mn);
            m_i[r] = mn;
        }
        float ps[4] = {0.f, 0.f, 0.f, 0.f};
        #pragma unroll
        for (int nt = 0; nt < 4; nt++)
            #pragma unroll
            for (int r = 0; r < 4; r++) {
                float p = __expf(s[nt][r] - m_i[r]);
                ps[r] += p;
                p_lds[wave][quad * 4 + r][nt * 16 + l16] = f2bf(p);
            }
        #pragma unroll
        for (int off = 1; off < 16; off <<= 1)
            #pragma unroll
            for (int r = 0; r < 4; r++)
                ps[r] += __shfl_xor(ps[r], off);
        #pragma unroll
        for (int r = 0; r < 4; r++) l_i[r] = l_i[r] * alpha[r] + ps[r];
        #pragma unroll
        for (int ht = 0; ht < 4; ht++)
            #pragma unroll
            for (int r = 0; r < 4; r++)
                o[ht][r] *= alpha[r];
        #pragma unroll
        for (int ks = 0; ks < 2; ks++) {
            short8 pf = *(const short8*)&p_lds[wave][l16][ks * 32 + quad * 8];
            #pragma unroll
            for (int ht = 0; ht < 4; ht++) {
                short8 vf = *(const short8*)(VT + (size_t)(ht * 16 + l16) * 2048 + j0 + ks * 32 + quad * 8);
                o[ht] = __builtin_amdgcn_mfma_f32_16x16x32_bf16(pf, vf, o[ht], 0, 0, 0);
            }
        }
    }
    float* op = out + ((size_t)b * 2048 + q0 + wave * 16 + quad * 4) * 64 + l16;
    #pragma unroll
    for (int r = 0; r < 4; r++) {
        float inv = 1.0f / l_i[r];
        #pragma unroll
        for (int ht = 0; ht < 4; ht++)
            op[r * 64 + ht * 16] = o[ht][r] * inv;
    }
}

// ---------------------------------------------------------------------------
extern "C" void kernel_launch(void* const* d_in, const int* in_sizes, int n_in,
                              void* d_out, int out_size, void* d_ws, size_t ws_size,
                              hipStream_t stream) {
    const float* x  = (const float*)d_in[0];
    const float* Wq = (const float*)d_in[1];
    const float* Wk = (const float*)d_in[2];
    const float* Wv = (const float*)d_in[3];
    float* out = (float*)d_out;
    unsigned short* ws = (unsigned short*)d_ws;
    unsigned short* wT = ws + WT_OFF;

    wtrans_kernel<<<dim3(3, 16), 256, 0, stream>>>(Wq, Wk, Wv, wT);
    proj_fused_kernel<<<dim3(512), 256, 0, stream>>>(x, wT, ws);

    int ct = 0, S = 0;
    const int cands[5] = {2, 4, 8, 16, 32};
    for (int i = 0; i < 5; i++) {
        const int cc = cands[i];
        const int aa = 32 / cc;
        const int ss = cc * aa * (aa + 1) / 2;
        const size_t need = (size_t)BASE_BYTES + (size_t)4 * ss * (4096 + 128) * 4;
        if (need <= ws_size) { ct = cc; S = ss; break; }
    }
    if (ct) {
        float* Opart  = (float*)((char*)d_ws + BASE_BYTES);
        float* MLpart = Opart + (size_t)4 * S * 4096;
        attn_partial_kernel<<<dim3(32, 32 / ct, 4), 256, 0, stream>>>(ws, Opart, MLpart, ct, S);
        attn_combine_kernel<<<dim3(32, 4), 256, 0, stream>>>(Opart, MLpart, out, ct, S);
    } else {
        attn_mono_kernel<<<dim3(32, 4), 256, 0, stream>>>(ws, out);
    }
}

// Round 5
// 140.569 us; speedup vs baseline: 1.6601x; 1.0448x over previous
//
#include <hip/hip_runtime.h>

// B=4, T=2048, C=1024, H=64. fp32 in/out, bf16 MFMA internally.
// ws layout (u16 elements):
//   [0,        524288)  q  bf16  [b*2048+t][64]
//   [524288,  1048576)  k  bf16  [b*2048+t][64]
//   [1048576, 1572864)  vT bf16  [b][h][t]   (b*131072 + h*2048 + t)
//   [1572864, 1769472)  wT bf16  [sel][h][c] (sel*65536 + h*1024 + c)

typedef __attribute__((ext_vector_type(8))) short short8;
typedef __attribute__((ext_vector_type(4))) float f32x4;

#define NTOT 524288   // 8192*64
#define WT_OFF (3 * NTOT)

__device__ __forceinline__ unsigned short f2bf(float f) {
    unsigned int u = __builtin_bit_cast(unsigned int, f);
    return (unsigned short)((u + 0x7fffu + ((u >> 16) & 1u)) >> 16);
}

__device__ __forceinline__ short8 pack8(float4 a, float4 b) {
    short8 r;
    r[0] = (short)f2bf(a.x); r[1] = (short)f2bf(a.y);
    r[2] = (short)f2bf(a.z); r[3] = (short)f2bf(a.w);
    r[4] = (short)f2bf(b.x); r[5] = (short)f2bf(b.y);
    r[6] = (short)f2bf(b.z); r[7] = (short)f2bf(b.w);
    return r;
}

// ---------------------------------------------------------------------------
// Kernel 1: transpose W (fp32 [1024][64]) -> wT bf16 [64][1024], x3 matrices
// (unchanged, round-4-proven)
// ---------------------------------------------------------------------------
__global__ __launch_bounds__(256) void wtrans_kernel(
    const float* __restrict__ Wq, const float* __restrict__ Wk,
    const float* __restrict__ Wv, unsigned short* __restrict__ wt)
{
    const int sel = blockIdx.x;
    const int c0  = blockIdx.y * 64;
    const float* W = (sel == 0) ? Wq : ((sel == 1) ? Wk : Wv);
    __shared__ unsigned short tile[64][72];
    const int tid = threadIdx.x;
    {
        const int c  = tid >> 2;
        const int hg = (tid & 3) * 16;
        const float* src = W + (size_t)(c0 + c) * 64 + hg;
        #pragma unroll
        for (int i = 0; i < 16; i++) tile[c][hg + i] = f2bf(src[i]);
    }
    __syncthreads();
    {
        const int h  = tid >> 2;
        const int cg = (tid & 3) * 16;
        unsigned short* dst = wt + ((size_t)sel * 64 + h) * 1024 + c0 + cg;
        #pragma unroll
        for (int i = 0; i < 16; i++) dst[i] = tile[cg + i][h];
    }
}

// ---------------------------------------------------------------------------
// Kernel 2: fused projections, cross-wave split-K (unchanged, round-4-proven)
// ---------------------------------------------------------------------------
__global__ __launch_bounds__(256) void proj_fused_kernel(
    const float* __restrict__ x, const unsigned short* __restrict__ wt,
    unsigned short* __restrict__ ws)
{
    const int m0   = blockIdx.x * 16;
    const int tid  = threadIdx.x;
    const int wave = tid >> 6, lane = tid & 63;
    const int quad = lane >> 4, l16 = lane & 15;

    const unsigned short* wq = wt;
    const unsigned short* wk = wt + 65536;
    const unsigned short* wv = wt + 131072;

    __shared__ float redq[4][16][65];   // [wave][t][h]
    __shared__ float redk[4][16][65];   // [wave][t][h]
    __shared__ float redv[4][64][17];   // [wave][h][t]

    f32x4 aq[4] = {}, ak[4] = {}, av[4] = {};

    const int kbase = wave * 256;
    const float* xrow = x + (size_t)(m0 + l16) * 1024 + kbase + quad * 8;
    float4 xa = *(const float4*)(xrow);
    float4 xb = *(const float4*)(xrow + 4);
    for (int kk = 0; kk < 256; kk += 32) {
        const int nk = (kk + 32) & 255;     // wraps on last iter (unused)
        float4 na = *(const float4*)(xrow + nk);
        float4 nb = *(const float4*)(xrow + nk + 4);
        short8 af = pack8(xa, xb);
        const int wo = kbase + kk + quad * 8;
        #pragma unroll
        for (int nt = 0; nt < 4; nt++) {
            const size_t ro = (size_t)(nt * 16 + l16) * 1024 + wo;
            short8 bq = *(const short8*)(wq + ro);
            short8 bk = *(const short8*)(wk + ro);
            short8 bv = *(const short8*)(wv + ro);
            aq[nt] = __builtin_amdgcn_mfma_f32_16x16x32_bf16(af, bq, aq[nt], 0, 0, 0);
            ak[nt] = __builtin_amdgcn_mfma_f32_16x16x32_bf16(af, bk, ak[nt], 0, 0, 0);
            av[nt] = __builtin_amdgcn_mfma_f32_16x16x32_bf16(bv, af, av[nt], 0, 0, 0);
        }
        xa = na; xb = nb;
    }
    #pragma unroll
    for (int nt = 0; nt < 4; nt++)
        #pragma unroll
        for (int r = 0; r < 4; r++) {
            redq[wave][quad * 4 + r][nt * 16 + l16] = aq[nt][r];
            redk[wave][quad * 4 + r][nt * 16 + l16] = ak[nt][r];
            redv[wave][nt * 16 + quad * 4 + r][l16] = av[nt][r];
        }
    __syncthreads();

    const int b   = m0 >> 11;
    const int tb0 = m0 & 2047;
    {   // q/k: thread -> (row = tid>>4, h0 = (tid&15)*4)
        const int row = tid >> 4, h0 = (tid & 15) * 4;
        #pragma unroll
        for (int i = 0; i < 4; i++) {
            const int h = h0 + i;
            float sq = redq[0][row][h] + redq[1][row][h]
                     + redq[2][row][h] + redq[3][row][h];
            float sk = redk[0][row][h] + redk[1][row][h]
                     + redk[2][row][h] + redk[3][row][h];
            ws[       (size_t)(m0 + row) * 64 + h] = f2bf(sq);
            ws[NTOT + (size_t)(m0 + row) * 64 + h] = f2bf(sk);
        }
    }
    {   // vT: thread -> (h = tid>>2, t4 = (tid&3)*4)
        const int h = tid >> 2, t4 = (tid & 3) * 4;
        unsigned short* vdst = ws + 2 * NTOT + (size_t)b * 131072
                             + (size_t)h * 2048 + tb0;
        #pragma unroll
        for (int i = 0; i < 4; i++) {
            const int t = t4 + i;
            float sv = redv[0][h][t] + redv[1][h][t]
                     + redv[2][h][t] + redv[3][h][t];
            vdst[t] = f2bf(sv);
        }
    }
}

// ---------------------------------------------------------------------------
// Kernel 3: fused flash attention with IN-BLOCK K-split.
// Block = 256 threads = 4 waves, all covering the SAME 16 q-rows; wave w
// processes k-tiles t = w, w+4, ... with its own online-softmax state.
// Cross-wave combine via LDS at the end — no global partials, no 2nd kernel.
// grid = (128, 4) = 512 blocks (2/CU); critical path <= 8 k-tile iterations.
// ---------------------------------------------------------------------------
__global__ __launch_bounds__(256) void attn_fused_kernel(
    const unsigned short* __restrict__ ws, float* __restrict__ out)
{
    const int qt = blockIdx.x;        // 16-row q tile, 0..127
    const int b  = blockIdx.y;
    const int q0 = qt * 16;
    const int tid  = threadIdx.x;
    const int wave = tid >> 6, lane = tid & 63;
    const int quad = lane >> 4, l16 = lane & 15;

    const unsigned short* Q  = ws + (size_t)b * 131072;
    const unsigned short* K  = ws + NTOT + (size_t)b * 131072;
    const unsigned short* VT = ws + 2 * NTOT + (size_t)b * 131072;

    __shared__ unsigned short p_lds[4][16][72];  // per-wave P scratch
    __shared__ float o_red[4][16][68];           // per-wave partial O
    __shared__ float ml_red[4][2][16];           // per-wave m / l

    // Q fragments: all 4 waves load the SAME 16 q-rows
    const int qrow = q0 + l16;
    short8 qf0 = *(const short8*)(Q + (size_t)qrow * 64 + quad * 8);
    short8 qf1 = *(const short8*)(Q + (size_t)qrow * 64 + 32 + quad * 8);

    f32x4 o[4] = {};
    float m_i[4], l_i[4];
    #pragma unroll
    for (int r = 0; r < 4; r++) { m_i[r] = -1e30f; l_i[r] = 0.f; }

    const int qi = q0 + quad * 4;
    const int nk = (qt >> 2) + 1;     // # of 64-wide k tiles for this q tile

    for (int t = wave; t < nk; t += 4) {
        const int j0 = t * 64;
        // ---- S = Q K^T (16 x 64) ----
        f32x4 s[4] = {};
        #pragma unroll
        for (int nt = 0; nt < 4; nt++) {
            const unsigned short* kp = K + (size_t)(j0 + nt * 16 + l16) * 64 + quad * 8;
            short8 kf0 = *(const short8*)(kp);
            short8 kf1 = *(const short8*)(kp + 32);
            s[nt] = __builtin_amdgcn_mfma_f32_16x16x32_bf16(qf0, kf0, s[nt], 0, 0, 0);
            s[nt] = __builtin_amdgcn_mfma_f32_16x16x32_bf16(qf1, kf1, s[nt], 0, 0, 0);
        }
        // ---- scale + causal mask + (==0 -> -inf) quirk ----
        float pm[4] = {-1e30f, -1e30f, -1e30f, -1e30f};
        #pragma unroll
        for (int nt = 0; nt < 4; nt++) {
            const int kj = j0 + nt * 16 + l16;
            #pragma unroll
            for (int r = 0; r < 4; r++) {
                float v = s[nt][r] * 0.125f;
                v = (kj > qi + r || v == 0.0f) ? -1e30f : v;
                s[nt][r] = v;
                pm[r] = fmaxf(pm[r], v);
            }
        }
        #pragma unroll
        for (int off = 1; off < 16; off <<= 1)
            #pragma unroll
            for (int r = 0; r < 4; r++)
                pm[r] = fmaxf(pm[r], __shfl_xor(pm[r], off));
        float alpha[4];
        #pragma unroll
        for (int r = 0; r < 4; r++) {
            float mn = fmaxf(m_i[r], pm[r]);
            alpha[r] = __expf(m_i[r] - mn);   // first iter: exp(-1e30)=0
            m_i[r] = mn;
        }
        // ---- P = exp(S - m), row-sum, stash in per-wave LDS ----
        float ps[4] = {0.f, 0.f, 0.f, 0.f};
        #pragma unroll
        for (int nt = 0; nt < 4; nt++)
            #pragma unroll
            for (int r = 0; r < 4; r++) {
                float p = __expf(s[nt][r] - m_i[r]);
                ps[r] += p;
                p_lds[wave][quad * 4 + r][nt * 16 + l16] = f2bf(p);
            }
        #pragma unroll
        for (int off = 1; off < 16; off <<= 1)
            #pragma unroll
            for (int r = 0; r < 4; r++)
                ps[r] += __shfl_xor(ps[r], off);
        #pragma unroll
        for (int r = 0; r < 4; r++) l_i[r] = l_i[r] * alpha[r] + ps[r];
        #pragma unroll
        for (int ht = 0; ht < 4; ht++)
            #pragma unroll
            for (int r = 0; r < 4; r++)
                o[ht][r] *= alpha[r];
        // ---- O += P V (per-wave LDS, no barrier needed) ----
        #pragma unroll
        for (int ks = 0; ks < 2; ks++) {
            short8 pf = *(const short8*)&p_lds[wave][l16][ks * 32 + quad * 8];
            #pragma unroll
            for (int ht = 0; ht < 4; ht++) {
                short8 vf = *(const short8*)(VT + (size_t)(ht * 16 + l16) * 2048 + j0 + ks * 32 + quad * 8);
                o[ht] = __builtin_amdgcn_mfma_f32_16x16x32_bf16(pf, vf, o[ht], 0, 0, 0);
            }
        }
    }

    // ---- stash per-wave partial state (scalar, proven style) ----
    #pragma unroll
    for (int ht = 0; ht < 4; ht++)
        #pragma unroll
        for (int r = 0; r < 4; r++)
            o_red[wave][quad * 4 + r][ht * 16 + l16] = o[ht][r];
    if (l16 == 0) {
        #pragma unroll
        for (int r = 0; r < 4; r++) {
            ml_red[wave][0][quad * 4 + r] = m_i[r];
            ml_red[wave][1][quad * 4 + r] = l_i[r];
        }
    }
    __syncthreads();

    // ---- cross-wave combine: thread -> (row = tid>>4, col0 = (tid&15)*4) ----
    const int row = tid >> 4, c0 = (tid & 15) * 4;
    float m0w = ml_red[0][0][row], m1w = ml_red[1][0][row];
    float m2w = ml_red[2][0][row], m3w = ml_red[3][0][row];
    float M = fmaxf(fmaxf(m0w, m1w), fmaxf(m2w, m3w));
    float w0 = __expf(m0w - M), w1 = __expf(m1w - M);
    float w2 = __expf(m2w - M), w3 = __expf(m3w - M);
    float l = w0 * ml_red[0][1][row] + w1 * ml_red[1][1][row]
            + w2 * ml_red[2][1][row] + w3 * ml_red[3][1][row];
    const float inv = 1.0f / l;
    float* op = out + ((size_t)b * 2048 + q0 + row) * 64 + c0;
    #pragma unroll
    for (int i = 0; i < 4; i++) {
        const int col = c0 + i;
        float sv = w0 * o_red[0][row][col] + w1 * o_red[1][row][col]
                 + w2 * o_red[2][row][col] + w3 * o_red[3][row][col];
        op[i] = sv * inv;
    }
}

// ---------------------------------------------------------------------------
extern "C" void kernel_launch(void* const* d_in, const int* in_sizes, int n_in,
                              void* d_out, int out_size, void* d_ws, size_t ws_size,
                              hipStream_t stream) {
    const float* x  = (const float*)d_in[0];
    const float* Wq = (const float*)d_in[1];
    const float* Wk = (const float*)d_in[2];
    const float* Wv = (const float*)d_in[3];
    float* out = (float*)d_out;
    unsigned short* ws = (unsigned short*)d_ws;
    unsigned short* wT = ws + WT_OFF;

    wtrans_kernel<<<dim3(3, 16), 256, 0, stream>>>(Wq, Wk, Wv, wT);
    proj_fused_kernel<<<dim3(512), 256, 0, stream>>>(x, wT, ws);
    attn_fused_kernel<<<dim3(128, 4), 256, 0, stream>>>(ws, out);
}

// Round 6
// 122.566 us; speedup vs baseline: 1.9040x; 1.1469x over previous
//
#include <hip/hip_runtime.h>

// B=4, T=2048, C=1024, H=64. fp32 in/out, bf16 MFMA internally.
// ws layout (u16 elements):
//   [0,        524288)  q  bf16  [b*2048+t][64]
//   [524288,  1048576)  k  bf16  [b*2048+t][64]
//   [1048576, 1572864)  vT bf16  [b][h][t]   (b*131072 + h*2048 + t)
//   [1572864, 1769472)  wT bf16  [sel][h][c] (sel*65536 + h*1024 + c)

typedef __attribute__((ext_vector_type(8))) short short8;
typedef __attribute__((ext_vector_type(4))) float f32x4;

#define NTOT 524288   // 8192*64
#define WT_OFF (3 * NTOT)

__device__ __forceinline__ unsigned short f2bf(float f) {
    unsigned int u = __builtin_bit_cast(unsigned int, f);
    return (unsigned short)((u + 0x7fffu + ((u >> 16) & 1u)) >> 16);
}

__device__ __forceinline__ short8 pack8(float4 a, float4 b) {
    short8 r;
    r[0] = (short)f2bf(a.x); r[1] = (short)f2bf(a.y);
    r[2] = (short)f2bf(a.z); r[3] = (short)f2bf(a.w);
    r[4] = (short)f2bf(b.x); r[5] = (short)f2bf(b.y);
    r[6] = (short)f2bf(b.z); r[7] = (short)f2bf(b.w);
    return r;
}

// ---------------------------------------------------------------------------
// Kernel 1: transpose W (fp32 [1024][64]) -> wT bf16 [64][1024], x3 matrices
// (unchanged, proven)
// ---------------------------------------------------------------------------
__global__ __launch_bounds__(256) void wtrans_kernel(
    const float* __restrict__ Wq, const float* __restrict__ Wk,
    const float* __restrict__ Wv, unsigned short* __restrict__ wt)
{
    const int sel = blockIdx.x;
    const int c0  = blockIdx.y * 64;
    const float* W = (sel == 0) ? Wq : ((sel == 1) ? Wk : Wv);
    __shared__ unsigned short tile[64][72];
    const int tid = threadIdx.x;
    {
        const int c  = tid >> 2;
        const int hg = (tid & 3) * 16;
        const float* src = W + (size_t)(c0 + c) * 64 + hg;
        #pragma unroll
        for (int i = 0; i < 16; i++) tile[c][hg + i] = f2bf(src[i]);
    }
    __syncthreads();
    {
        const int h  = tid >> 2;
        const int cg = (tid & 3) * 16;
        unsigned short* dst = wt + ((size_t)sel * 64 + h) * 1024 + c0 + cg;
        #pragma unroll
        for (int i = 0; i < 16; i++) dst[i] = tile[cg + i][h];
    }
}

// ---------------------------------------------------------------------------
// Kernel 2: fused projections, 32 t-columns per wave + cross-wave split-K.
// Block = 256 threads = 4 waves over the SAME 32 t-rows; wave w covers
// K in [w*256, (w+1)*256) (8 iters, 24 MFMA + 16 loads each). W traffic
// halves vs the 16-col version (96 MB total). Staged LDS reduction:
// q/k first, barrier, LDS reused for v. grid = 256 blocks (1/CU).
// ---------------------------------------------------------------------------
__global__ __launch_bounds__(256) void proj_fused_kernel(
    const float* __restrict__ x, const unsigned short* __restrict__ wt,
    unsigned short* __restrict__ ws)
{
    const int m0   = blockIdx.x * 32;
    const int tid  = threadIdx.x;
    const int wave = tid >> 6, lane = tid & 63;
    const int quad = lane >> 4, l16 = lane & 15;

    const unsigned short* wq = wt;
    const unsigned short* wk = wt + 65536;
    const unsigned short* wv = wt + 131072;

    // q/k partials: red[sel][wave][t_local 0..31][h 0..64(pad 65)]
    // v partials reuse the same memory: redv[(wave*64 + h)*33 + t_local]
    __shared__ float red[2][4][32][65];   // 66.6 KB
    float* redv = &red[0][0][0][0];       // needs 4*64*33 = 8448 floats (33.8 KB)

    f32x4 aq[2][4] = {}, ak[2][4] = {}, av[4][2] = {};

    const int kbase = wave * 256;
    const float* xrow0 = x + (size_t)(m0 + l16) * 1024 + kbase + quad * 8;
    const float* xrow1 = xrow0 + (size_t)16 * 1024;
    float4 xa0 = *(const float4*)(xrow0);
    float4 xb0 = *(const float4*)(xrow0 + 4);
    float4 xa1 = *(const float4*)(xrow1);
    float4 xb1 = *(const float4*)(xrow1 + 4);
    for (int kk = 0; kk < 256; kk += 32) {
        const int nk = (kk + 32) & 255;     // wraps on last iter (unused)
        float4 na0 = *(const float4*)(xrow0 + nk);
        float4 nb0 = *(const float4*)(xrow0 + nk + 4);
        float4 na1 = *(const float4*)(xrow1 + nk);
        float4 nb1 = *(const float4*)(xrow1 + nk + 4);
        short8 af0 = pack8(xa0, xb0);
        short8 af1 = pack8(xa1, xb1);
        const int wo = kbase + kk + quad * 8;
        #pragma unroll
        for (int nt = 0; nt < 4; nt++) {
            const size_t ro = (size_t)(nt * 16 + l16) * 1024 + wo;
            short8 bq = *(const short8*)(wq + ro);
            short8 bk = *(const short8*)(wk + ro);
            short8 bv = *(const short8*)(wv + ro);
            aq[0][nt] = __builtin_amdgcn_mfma_f32_16x16x32_bf16(af0, bq, aq[0][nt], 0, 0, 0);
            aq[1][nt] = __builtin_amdgcn_mfma_f32_16x16x32_bf16(af1, bq, aq[1][nt], 0, 0, 0);
            ak[0][nt] = __builtin_amdgcn_mfma_f32_16x16x32_bf16(af0, bk, ak[0][nt], 0, 0, 0);
            ak[1][nt] = __builtin_amdgcn_mfma_f32_16x16x32_bf16(af1, bk, ak[1][nt], 0, 0, 0);
            av[nt][0] = __builtin_amdgcn_mfma_f32_16x16x32_bf16(bv, af0, av[nt][0], 0, 0, 0);
            av[nt][1] = __builtin_amdgcn_mfma_f32_16x16x32_bf16(bv, af1, av[nt][1], 0, 0, 0);
        }
        xa0 = na0; xb0 = nb0; xa1 = na1; xb1 = nb1;
    }
    // ---- stash q/k partials (scalar, proven style) ----
    #pragma unroll
    for (int tf = 0; tf < 2; tf++)
        #pragma unroll
        for (int nt = 0; nt < 4; nt++)
            #pragma unroll
            for (int r = 0; r < 4; r++) {
                red[0][wave][tf * 16 + quad * 4 + r][nt * 16 + l16] = aq[tf][nt][r];
                red[1][wave][tf * 16 + quad * 4 + r][nt * 16 + l16] = ak[tf][nt][r];
            }
    __syncthreads();
    // ---- reduce + store q/k: thread -> (row = tid>>3, h0 = (tid&7)*8) ----
    {
        const int row = tid >> 3, h0 = (tid & 7) * 8;
        #pragma unroll
        for (int i = 0; i < 8; i++) {
            const int h = h0 + i;
            float sq = red[0][0][row][h] + red[0][1][row][h]
                     + red[0][2][row][h] + red[0][3][row][h];
            float sk = red[1][0][row][h] + red[1][1][row][h]
                     + red[1][2][row][h] + red[1][3][row][h];
            ws[       (size_t)(m0 + row) * 64 + h] = f2bf(sq);
            ws[NTOT + (size_t)(m0 + row) * 64 + h] = f2bf(sk);
        }
    }
    __syncthreads();   // q/k reads done before v overwrites the buffer
    // ---- stash v partials: redv[(wave*64 + h)*33 + t_local] ----
    #pragma unroll
    for (int nt = 0; nt < 4; nt++)
        #pragma unroll
        for (int tf = 0; tf < 2; tf++)
            #pragma unroll
            for (int r = 0; r < 4; r++)
                redv[(wave * 64 + nt * 16 + quad * 4 + r) * 33 + tf * 16 + l16]
                    = av[nt][tf][r];
    __syncthreads();
    // ---- reduce + store vT: thread -> (h = tid>>2, t0 = (tid&3)*8) ----
    {
        const int b   = m0 >> 11;
        const int tb0 = m0 & 2047;
        const int h = tid >> 2, t0 = (tid & 3) * 8;
        unsigned short* vdst = ws + 2 * NTOT + (size_t)b * 131072
                             + (size_t)h * 2048 + tb0;
        #pragma unroll
        for (int i = 0; i < 8; i++) {
            const int t = t0 + i;
            float sv = redv[(0 * 64 + h) * 33 + t] + redv[(1 * 64 + h) * 33 + t]
                     + redv[(2 * 64 + h) * 33 + t] + redv[(3 * 64 + h) * 33 + t];
            vdst[t] = f2bf(sv);
        }
    }
}

// ---------------------------------------------------------------------------
// Kernel 3: fused flash attention, in-block K-split (round-5-proven body)
// + XCD-locality swizzle: 1D grid of 512; xcd = B&7 serves exactly one
// batch (b = xcd&3), so each XCD's K/V/Q working set (1.5 MB) stays in
// its own 4 MB L2 instead of bouncing through L3.
// ---------------------------------------------------------------------------
__global__ __launch_bounds__(256) void attn_fused_kernel(
    const unsigned short* __restrict__ ws, float* __restrict__ out)
{
    const int B    = blockIdx.x;
    const int xcd  = B & 7;
    const int slot = B >> 3;
    const int b    = xcd & 3;
    const int qt   = (slot << 1) | (xcd >> 2);   // 0..127
    const int q0 = qt * 16;
    const int tid  = threadIdx.x;
    const int wave = tid >> 6, lane = tid & 63;
    const int quad = lane >> 4, l16 = lane & 15;

    const unsigned short* Q  = ws + (size_t)b * 131072;
    const unsigned short* K  = ws + NTOT + (size_t)b * 131072;
    const unsigned short* VT = ws + 2 * NTOT + (size_t)b * 131072;

    __shared__ unsigned short p_lds[4][16][72];  // per-wave P scratch
    __shared__ float o_red[4][16][68];           // per-wave partial O
    __shared__ float ml_red[4][2][16];           // per-wave m / l

    const int qrow = q0 + l16;
    short8 qf0 = *(const short8*)(Q + (size_t)qrow * 64 + quad * 8);
    short8 qf1 = *(const short8*)(Q + (size_t)qrow * 64 + 32 + quad * 8);

    f32x4 o[4] = {};
    float m_i[4], l_i[4];
    #pragma unroll
    for (int r = 0; r < 4; r++) { m_i[r] = -1e30f; l_i[r] = 0.f; }

    const int qi = q0 + quad * 4;
    const int nkt = (qt >> 2) + 1;

    for (int t = wave; t < nkt; t += 4) {
        const int j0 = t * 64;
        f32x4 s[4] = {};
        #pragma unroll
        for (int nt = 0; nt < 4; nt++) {
            const unsigned short* kp = K + (size_t)(j0 + nt * 16 + l16) * 64 + quad * 8;
            short8 kf0 = *(const short8*)(kp);
            short8 kf1 = *(const short8*)(kp + 32);
            s[nt] = __builtin_amdgcn_mfma_f32_16x16x32_bf16(qf0, kf0, s[nt], 0, 0, 0);
            s[nt] = __builtin_amdgcn_mfma_f32_16x16x32_bf16(qf1, kf1, s[nt], 0, 0, 0);
        }
        float pm[4] = {-1e30f, -1e30f, -1e30f, -1e30f};
        #pragma unroll
        for (int nt = 0; nt < 4; nt++) {
            const int kj = j0 + nt * 16 + l16;
            #pragma unroll
            for (int r = 0; r < 4; r++) {
                float v = s[nt][r] * 0.125f;
                v = (kj > qi + r || v == 0.0f) ? -1e30f : v;
                s[nt][r] = v;
                pm[r] = fmaxf(pm[r], v);
            }
        }
        #pragma unroll
        for (int off = 1; off < 16; off <<= 1)
            #pragma unroll
            for (int r = 0; r < 4; r++)
                pm[r] = fmaxf(pm[r], __shfl_xor(pm[r], off));
        float alpha[4];
        #pragma unroll
        for (int r = 0; r < 4; r++) {
            float mn = fmaxf(m_i[r], pm[r]);
            alpha[r] = __expf(m_i[r] - mn);
            m_i[r] = mn;
        }
        float ps[4] = {0.f, 0.f, 0.f, 0.f};
        #pragma unroll
        for (int nt = 0; nt < 4; nt++)
            #pragma unroll
            for (int r = 0; r < 4; r++) {
                float p = __expf(s[nt][r] - m_i[r]);
                ps[r] += p;
                p_lds[wave][quad * 4 + r][nt * 16 + l16] = f2bf(p);
            }
        #pragma unroll
        for (int off = 1; off < 16; off <<= 1)
            #pragma unroll
            for (int r = 0; r < 4; r++)
                ps[r] += __shfl_xor(ps[r], off);
        #pragma unroll
        for (int r = 0; r < 4; r++) l_i[r] = l_i[r] * alpha[r] + ps[r];
        #pragma unroll
        for (int ht = 0; ht < 4; ht++)
            #pragma unroll
            for (int r = 0; r < 4; r++)
                o[ht][r] *= alpha[r];
        #pragma unroll
        for (int ks = 0; ks < 2; ks++) {
            short8 pf = *(const short8*)&p_lds[wave][l16][ks * 32 + quad * 8];
            #pragma unroll
            for (int ht = 0; ht < 4; ht++) {
                short8 vf = *(const short8*)(VT + (size_t)(ht * 16 + l16) * 2048 + j0 + ks * 32 + quad * 8);
                o[ht] = __builtin_amdgcn_mfma_f32_16x16x32_bf16(pf, vf, o[ht], 0, 0, 0);
            }
        }
    }

    #pragma unroll
    for (int ht = 0; ht < 4; ht++)
        #pragma unroll
        for (int r = 0; r < 4; r++)
            o_red[wave][quad * 4 + r][ht * 16 + l16] = o[ht][r];
    if (l16 == 0) {
        #pragma unroll
        for (int r = 0; r < 4; r++) {
            ml_red[wave][0][quad * 4 + r] = m_i[r];
            ml_red[wave][1][quad * 4 + r] = l_i[r];
        }
    }
    __syncthreads();

    const int row = tid >> 4, c0 = (tid & 15) * 4;
    float m0w = ml_red[0][0][row], m1w = ml_red[1][0][row];
    float m2w = ml_red[2][0][row], m3w = ml_red[3][0][row];
    float M = fmaxf(fmaxf(m0w, m1w), fmaxf(m2w, m3w));
    float w0 = __expf(m0w - M), w1 = __expf(m1w - M);
    float w2 = __expf(m2w - M), w3 = __expf(m3w - M);
    float l = w0 * ml_red[0][1][row] + w1 * ml_red[1][1][row]
            + w2 * ml_red[2][1][row] + w3 * ml_red[3][1][row];
    const float inv = 1.0f / l;
    float* op = out + ((size_t)b * 2048 + q0 + row) * 64 + c0;
    #pragma unroll
    for (int i = 0; i < 4; i++) {
        const int col = c0 + i;
        float sv = w0 * o_red[0][row][col] + w1 * o_red[1][row][col]
                 + w2 * o_red[2][row][col] + w3 * o_red[3][row][col];
        op[i] = sv * inv;
    }
}

// ---------------------------------------------------------------------------
extern "C" void kernel_launch(void* const* d_in, const int* in_sizes, int n_in,
                              void* d_out, int out_size, void* d_ws, size_t ws_size,
                              hipStream_t stream) {
    const float* x  = (const float*)d_in[0];
    const float* Wq = (const float*)d_in[1];
    const float* Wk = (const float*)d_in[2];
    const float* Wv = (const float*)d_in[3];
    float* out = (float*)d_out;
    unsigned short* ws = (unsigned short*)d_ws;
    unsigned short* wT = ws + WT_OFF;

    wtrans_kernel<<<dim3(3, 16), 256, 0, stream>>>(Wq, Wk, Wv, wT);
    proj_fused_kernel<<<dim3(256), 256, 0, stream>>>(x, wT, ws);
    attn_fused_kernel<<<dim3(512), 256, 0, stream>>>(ws, out);
}

// Round 7
// 120.094 us; speedup vs baseline: 1.9432x; 1.0206x over previous
//
#include <hip/hip_runtime.h>

// B=4, T=2048, C=1024, H=64. fp32 in/out, bf16 MFMA internally.
// ws layout (u16 elements):
//   [0,        524288)  q  bf16  [b*2048+t][64]
//   [524288,  1048576)  k  bf16  [b*2048+t][64]
//   [1048576, 1572864)  vT bf16  [b][h][t]   (b*131072 + h*2048 + t)
//   [1572864, 1769472)  wT bf16  [sel][h][c] (sel*65536 + h*1024 + c)

typedef __attribute__((ext_vector_type(8))) short short8;
typedef __attribute__((ext_vector_type(4))) float f32x4;

#define NTOT 524288   // 8192*64
#define WT_OFF (3 * NTOT)

__device__ __forceinline__ unsigned short f2bf(float f) {
    unsigned int u = __builtin_bit_cast(unsigned int, f);
    return (unsigned short)((u + 0x7fffu + ((u >> 16) & 1u)) >> 16);
}

__device__ __forceinline__ short8 pack8(float4 a, float4 b) {
    short8 r;
    r[0] = (short)f2bf(a.x); r[1] = (short)f2bf(a.y);
    r[2] = (short)f2bf(a.z); r[3] = (short)f2bf(a.w);
    r[4] = (short)f2bf(b.x); r[5] = (short)f2bf(b.y);
    r[6] = (short)f2bf(b.z); r[7] = (short)f2bf(b.w);
    return r;
}

// ---------------------------------------------------------------------------
// Kernel 1: transpose W (fp32 [1024][64]) -> wT bf16 [64][1024], x3 matrices
// (unchanged, proven)
// ---------------------------------------------------------------------------
__global__ __launch_bounds__(256) void wtrans_kernel(
    const float* __restrict__ Wq, const float* __restrict__ Wk,
    const float* __restrict__ Wv, unsigned short* __restrict__ wt)
{
    const int sel = blockIdx.x;
    const int c0  = blockIdx.y * 64;
    const float* W = (sel == 0) ? Wq : ((sel == 1) ? Wk : Wv);
    __shared__ unsigned short tile[64][72];
    const int tid = threadIdx.x;
    {
        const int c  = tid >> 2;
        const int hg = (tid & 3) * 16;
        const float* src = W + (size_t)(c0 + c) * 64 + hg;
        #pragma unroll
        for (int i = 0; i < 16; i++) tile[c][hg + i] = f2bf(src[i]);
    }
    __syncthreads();
    {
        const int h  = tid >> 2;
        const int cg = (tid & 3) * 16;
        unsigned short* dst = wt + ((size_t)sel * 64 + h) * 1024 + c0 + cg;
        #pragma unroll
        for (int i = 0; i < 16; i++) dst[i] = tile[cg + i][h];
    }
}

// ---------------------------------------------------------------------------
// Kernel 2: fused projections. 256 blocks x 512 threads (8 waves).
// Block covers 32 t-rows; wave w covers K in [w*128, (w+1)*128) -> 4 iters
// of (24 MFMA + 16 loads). Cross-wave reduction in 3 staged LDS phases
// (q, k, v) reusing one 67.6 KB buffer. 8 waves/CU = 2/SIMD.
// ---------------------------------------------------------------------------
__global__ __launch_bounds__(512) void proj_fused_kernel(
    const float* __restrict__ x, const unsigned short* __restrict__ wt,
    unsigned short* __restrict__ ws)
{
    const int m0   = blockIdx.x * 32;
    const int tid  = threadIdx.x;
    const int wave = tid >> 6, lane = tid & 63;   // wave 0..7
    const int quad = lane >> 4, l16 = lane & 15;

    const unsigned short* wq = wt;
    const unsigned short* wk = wt + 65536;
    const unsigned short* wv = wt + 131072;

    // shared scratch, reused per phase:
    //   q/k phases: [8][32][66] floats (idx (w*32+t)*66 + h)
    //   v phase:    [8][64][33] floats (idx (w*64+h)*33 + t)
    __shared__ float lds[16896];   // 67.6 KB

    f32x4 aq[2][4] = {}, ak[2][4] = {}, av[4][2] = {};

    const int kbase = wave * 128;
    const float* xrow0 = x + (size_t)(m0 + l16) * 1024 + kbase + quad * 8;
    const float* xrow1 = xrow0 + (size_t)16 * 1024;
    float4 xa0 = *(const float4*)(xrow0);
    float4 xb0 = *(const float4*)(xrow0 + 4);
    float4 xa1 = *(const float4*)(xrow1);
    float4 xb1 = *(const float4*)(xrow1 + 4);
    for (int kk = 0; kk < 128; kk += 32) {
        const int nk = (kk + 32) & 127;     // wraps on last iter (unused)
        float4 na0 = *(const float4*)(xrow0 + nk);
        float4 nb0 = *(const float4*)(xrow0 + nk + 4);
        float4 na1 = *(const float4*)(xrow1 + nk);
        float4 nb1 = *(const float4*)(xrow1 + nk + 4);
        short8 af0 = pack8(xa0, xb0);
        short8 af1 = pack8(xa1, xb1);
        const int wo = kbase + kk + quad * 8;
        #pragma unroll
        for (int nt = 0; nt < 4; nt++) {
            const size_t ro = (size_t)(nt * 16 + l16) * 1024 + wo;
            short8 bq = *(const short8*)(wq + ro);
            short8 bk = *(const short8*)(wk + ro);
            short8 bv = *(const short8*)(wv + ro);
            aq[0][nt] = __builtin_amdgcn_mfma_f32_16x16x32_bf16(af0, bq, aq[0][nt], 0, 0, 0);
            aq[1][nt] = __builtin_amdgcn_mfma_f32_16x16x32_bf16(af1, bq, aq[1][nt], 0, 0, 0);
            ak[0][nt] = __builtin_amdgcn_mfma_f32_16x16x32_bf16(af0, bk, ak[0][nt], 0, 0, 0);
            ak[1][nt] = __builtin_amdgcn_mfma_f32_16x16x32_bf16(af1, bk, ak[1][nt], 0, 0, 0);
            av[nt][0] = __builtin_amdgcn_mfma_f32_16x16x32_bf16(bv, af0, av[nt][0], 0, 0, 0);
            av[nt][1] = __builtin_amdgcn_mfma_f32_16x16x32_bf16(bv, af1, av[nt][1], 0, 0, 0);
        }
        xa0 = na0; xb0 = nb0; xa1 = na1; xb1 = nb1;
    }

    const int b   = m0 >> 11;
    const int tb0 = m0 & 2047;
    const int rrow = tid >> 4, rh0 = (tid & 15) * 4;   // q/k reduce mapping

    // ---- phase Q: stash, reduce 8-way, store ----
    #pragma unroll
    for (int tf = 0; tf < 2; tf++)
        #pragma unroll
        for (int nt = 0; nt < 4; nt++)
            #pragma unroll
            for (int r = 0; r < 4; r++)
                lds[(wave * 32 + tf * 16 + quad * 4 + r) * 66 + nt * 16 + l16]
                    = aq[tf][nt][r];
    __syncthreads();
    {
        float s[4] = {0.f, 0.f, 0.f, 0.f};
        #pragma unroll
        for (int w = 0; w < 8; w++)
            #pragma unroll
            for (int i = 0; i < 4; i++)
                s[i] += lds[(w * 32 + rrow) * 66 + rh0 + i];
        #pragma unroll
        for (int i = 0; i < 4; i++)
            ws[(size_t)(m0 + rrow) * 64 + rh0 + i] = f2bf(s[i]);
    }
    __syncthreads();

    // ---- phase K ----
    #pragma unroll
    for (int tf = 0; tf < 2; tf++)
        #pragma unroll
        for (int nt = 0; nt < 4; nt++)
            #pragma unroll
            for (int r = 0; r < 4; r++)
                lds[(wave * 32 + tf * 16 + quad * 4 + r) * 66 + nt * 16 + l16]
                    = ak[tf][nt][r];
    __syncthreads();
    {
        float s[4] = {0.f, 0.f, 0.f, 0.f};
        #pragma unroll
        for (int w = 0; w < 8; w++)
            #pragma unroll
            for (int i = 0; i < 4; i++)
                s[i] += lds[(w * 32 + rrow) * 66 + rh0 + i];
        #pragma unroll
        for (int i = 0; i < 4; i++)
            ws[NTOT + (size_t)(m0 + rrow) * 64 + rh0 + i] = f2bf(s[i]);
    }
    __syncthreads();

    // ---- phase V: av[nt][tf][r] -> h = nt*16+quad*4+r, t = tf*16+l16 ----
    #pragma unroll
    for (int nt = 0; nt < 4; nt++)
        #pragma unroll
        for (int tf = 0; tf < 2; tf++)
            #pragma unroll
            for (int r = 0; r < 4; r++)
                lds[(wave * 64 + nt * 16 + quad * 4 + r) * 33 + tf * 16 + l16]
                    = av[nt][tf][r];
    __syncthreads();
    {
        const int h = tid >> 3, t0 = (tid & 7) * 4;
        unsigned short* vdst = ws + 2 * NTOT + (size_t)b * 131072
                             + (size_t)h * 2048 + tb0;
        float s[4] = {0.f, 0.f, 0.f, 0.f};
        #pragma unroll
        for (int w = 0; w < 8; w++)
            #pragma unroll
            for (int i = 0; i < 4; i++)
                s[i] += lds[(w * 64 + h) * 33 + t0 + i];
        #pragma unroll
        for (int i = 0; i < 4; i++)
            vdst[t0 + i] = f2bf(s[i]);
    }
}

// ---------------------------------------------------------------------------
// Kernel 3: fused flash attention, 8-way in-block K-split + XCD swizzle.
// 512 blocks x 512 threads (8 waves); all waves share the same 16 q-rows,
// wave w does k-tiles t = w, w+8, ... (makespan <= 4 iters). 8-way LDS
// combine. xcd = B&7 serves one batch -> K/V stay in that XCD's L2.
// ---------------------------------------------------------------------------
__global__ __launch_bounds__(512) void attn_fused_kernel(
    const unsigned short* __restrict__ ws, float* __restrict__ out)
{
    const int B    = blockIdx.x;
    const int xcd  = B & 7;
    const int slot = B >> 3;
    const int b    = xcd & 3;
    const int qt   = (slot << 1) | (xcd >> 2);   // 0..127
    const int q0 = qt * 16;
    const int tid  = threadIdx.x;
    const int wave = tid >> 6, lane = tid & 63;  // wave 0..7
    const int quad = lane >> 4, l16 = lane & 15;

    const unsigned short* Q  = ws + (size_t)b * 131072;
    const unsigned short* K  = ws + NTOT + (size_t)b * 131072;
    const unsigned short* VT = ws + 2 * NTOT + (size_t)b * 131072;

    __shared__ unsigned short p_lds[8][16][72];  // per-wave P scratch
    __shared__ float o_red[8][16][68];           // per-wave partial O
    __shared__ float ml_red[8][2][16];           // per-wave m / l

    const int qrow = q0 + l16;
    short8 qf0 = *(const short8*)(Q + (size_t)qrow * 64 + quad * 8);
    short8 qf1 = *(const short8*)(Q + (size_t)qrow * 64 + 32 + quad * 8);

    f32x4 o[4] = {};
    float m_i[4], l_i[4];
    #pragma unroll
    for (int r = 0; r < 4; r++) { m_i[r] = -1e30f; l_i[r] = 0.f; }

    const int qi = q0 + quad * 4;
    const int nkt = (qt >> 2) + 1;

    for (int t = wave; t < nkt; t += 8) {
        const int j0 = t * 64;
        f32x4 s[4] = {};
        #pragma unroll
        for (int nt = 0; nt < 4; nt++) {
            const unsigned short* kp = K + (size_t)(j0 + nt * 16 + l16) * 64 + quad * 8;
            short8 kf0 = *(const short8*)(kp);
            short8 kf1 = *(const short8*)(kp + 32);
            s[nt] = __builtin_amdgcn_mfma_f32_16x16x32_bf16(qf0, kf0, s[nt], 0, 0, 0);
            s[nt] = __builtin_amdgcn_mfma_f32_16x16x32_bf16(qf1, kf1, s[nt], 0, 0, 0);
        }
        float pm[4] = {-1e30f, -1e30f, -1e30f, -1e30f};
        #pragma unroll
        for (int nt = 0; nt < 4; nt++) {
            const int kj = j0 + nt * 16 + l16;
            #pragma unroll
            for (int r = 0; r < 4; r++) {
                float v = s[nt][r] * 0.125f;
                v = (kj > qi + r || v == 0.0f) ? -1e30f : v;  // causal + ==0 quirk
                s[nt][r] = v;
                pm[r] = fmaxf(pm[r], v);
            }
        }
        #pragma unroll
        for (int off = 1; off < 16; off <<= 1)
            #pragma unroll
            for (int r = 0; r < 4; r++)
                pm[r] = fmaxf(pm[r], __shfl_xor(pm[r], off));
        float alpha[4];
        #pragma unroll
        for (int r = 0; r < 4; r++) {
            float mn = fmaxf(m_i[r], pm[r]);
            alpha[r] = __expf(m_i[r] - mn);
            m_i[r] = mn;
        }
        float ps[4] = {0.f, 0.f, 0.f, 0.f};
        #pragma unroll
        for (int nt = 0; nt < 4; nt++)
            #pragma unroll
            for (int r = 0; r < 4; r++) {
                float p = __expf(s[nt][r] - m_i[r]);
                ps[r] += p;
                p_lds[wave][quad * 4 + r][nt * 16 + l16] = f2bf(p);
            }
        #pragma unroll
        for (int off = 1; off < 16; off <<= 1)
            #pragma unroll
            for (int r = 0; r < 4; r++)
                ps[r] += __shfl_xor(ps[r], off);
        #pragma unroll
        for (int r = 0; r < 4; r++) l_i[r] = l_i[r] * alpha[r] + ps[r];
        #pragma unroll
        for (int ht = 0; ht < 4; ht++)
            #pragma unroll
            for (int r = 0; r < 4; r++)
                o[ht][r] *= alpha[r];
        #pragma unroll
        for (int ks = 0; ks < 2; ks++) {
            short8 pf = *(const short8*)&p_lds[wave][l16][ks * 32 + quad * 8];
            #pragma unroll
            for (int ht = 0; ht < 4; ht++) {
                short8 vf = *(const short8*)(VT + (size_t)(ht * 16 + l16) * 2048 + j0 + ks * 32 + quad * 8);
                o[ht] = __builtin_amdgcn_mfma_f32_16x16x32_bf16(pf, vf, o[ht], 0, 0, 0);
            }
        }
    }

    // ---- stash per-wave partial state ----
    #pragma unroll
    for (int ht = 0; ht < 4; ht++)
        #pragma unroll
        for (int r = 0; r < 4; r++)
            o_red[wave][quad * 4 + r][ht * 16 + l16] = o[ht][r];
    if (l16 == 0) {
        #pragma unroll
        for (int r = 0; r < 4; r++) {
            ml_red[wave][0][quad * 4 + r] = m_i[r];
            ml_red[wave][1][quad * 4 + r] = l_i[r];
        }
    }
    __syncthreads();

    // ---- 8-way combine: thread -> (row = tid>>5, col0 = (tid&31)*2) ----
    const int row = tid >> 5, c0 = (tid & 31) * 2;
    float M = -1e30f;
    #pragma unroll
    for (int w = 0; w < 8; w++) M = fmaxf(M, ml_red[w][0][row]);
    float wgt[8];
    float l = 0.f;
    #pragma unroll
    for (int w = 0; w < 8; w++) {
        wgt[w] = __expf(ml_red[w][0][row] - M);
        l += wgt[w] * ml_red[w][1][row];
    }
    const float inv = 1.0f / l;
    float* op = out + ((size_t)b * 2048 + q0 + row) * 64 + c0;
    #pragma unroll
    for (int i = 0; i < 2; i++) {
        const int col = c0 + i;
        float sv = 0.f;
        #pragma unroll
        for (int w = 0; w < 8; w++) sv += wgt[w] * o_red[w][row][col];
        op[i] = sv * inv;
    }
}

// ---------------------------------------------------------------------------
extern "C" void kernel_launch(void* const* d_in, const int* in_sizes, int n_in,
                              void* d_out, int out_size, void* d_ws, size_t ws_size,
                              hipStream_t stream) {
    const float* x  = (const float*)d_in[0];
    const float* Wq = (const float*)d_in[1];
    const float* Wk = (const float*)d_in[2];
    const float* Wv = (const float*)d_in[3];
    float* out = (float*)d_out;
    unsigned short* ws = (unsigned short*)d_ws;
    unsigned short* wT = ws + WT_OFF;

    wtrans_kernel<<<dim3(3, 16), 256, 0, stream>>>(Wq, Wk, Wv, wT);
    proj_fused_kernel<<<dim3(256), 512, 0, stream>>>(x, wT, ws);
    attn_fused_kernel<<<dim3(512), 512, 0, stream>>>(ws, out);
}